// Round 4
// baseline (20088.538 us; speedup 1.0000x reference)
//
#include <hip/hip_runtime.h>

#define BB 4
#define CC 64
#define NNN 4096
#define OO 64
#define KK 20
#define EPSF 1e-5f

// ---------------- K1: xx[n] = sum_c x[c][n]^2 in f64 ----------------
__global__ __launch_bounds__(256) void xx_kernel(const float* __restrict__ x, double* __restrict__ xx) {
    int g = blockIdx.x * 256 + threadIdx.x;          // 0..B*N-1
    int b = g >> 12, n = g & (NNN - 1);
    const float* xp = x + (size_t)b * CC * NNN + n;
    double s = 0.0;
    for (int c = 0; c < CC; ++c) {
        double v = (double)xp[(size_t)c * NNN];
        s += v * v;
    }
    xx[g] = s;
}

// ---------------- K2: per-point projections A = x*w1a^T, Bv = x*(w1b-w1a)^T ----------------
__global__ __launch_bounds__(256) void proj_kernel(const float* __restrict__ x, const float* __restrict__ w1,
                                                   float* __restrict__ A, float* __restrict__ Bv) {
    __shared__ float xs[CC][64];       // [c][p]
    __shared__ float ws1[OO][129];     // padded
    int tid = threadIdx.x;
    int b = blockIdx.x >> 6;
    int p0 = (blockIdx.x & 63) << 6;
    const float* xb = x + (size_t)b * CC * NNN;
    for (int i = tid; i < CC * 16; i += 256) {
        int c = i >> 4, q = i & 15;
        *(float4*)&xs[c][q * 4] = *(const float4*)(xb + (size_t)c * NNN + p0 + q * 4);
    }
    for (int i = tid; i < OO * 32; i += 256) {
        int o = i >> 5, q = i & 31;
        float4 v = *(const float4*)(w1 + o * 128 + q * 4);
        ws1[o][q * 4 + 0] = v.x; ws1[o][q * 4 + 1] = v.y;
        ws1[o][q * 4 + 2] = v.z; ws1[o][q * 4 + 3] = v.w;
    }
    __syncthreads();
    int ti = tid >> 4, tj = tid & 15;
    float aA[4][4] = {{0.f}}, aD[4][4] = {{0.f}};
    for (int c = 0; c < CC; ++c) {
        float4 xv4 = *(const float4*)&xs[c][ti * 4];
        float xv[4] = {xv4.x, xv4.y, xv4.z, xv4.w};
        #pragma unroll
        for (int oo = 0; oo < 4; ++oo) {
            float wa = ws1[tj * 4 + oo][c];
            float wd = ws1[tj * 4 + oo][64 + c] - wa;
            #pragma unroll
            for (int pp = 0; pp < 4; ++pp) {
                aA[pp][oo] = fmaf(xv[pp], wa, aA[pp][oo]);
                aD[pp][oo] = fmaf(xv[pp], wd, aD[pp][oo]);
            }
        }
    }
    size_t base = ((size_t)b * NNN + p0) * 64;
    #pragma unroll
    for (int pp = 0; pp < 4; ++pp) {
        int p = ti * 4 + pp;
        *(float4*)(A  + base + (size_t)p * 64 + tj * 4) = make_float4(aA[pp][0], aA[pp][1], aA[pp][2], aA[pp][3]);
        *(float4*)(Bv + base + (size_t)p * 64 + tj * 4) = make_float4(aD[pp][0], aD[pp][1], aD[pp][2], aD[pp][3]);
    }
}

// ---------------- K3: fused f64 distances + register top-20 (anchored VGPR list) ----------------
// 1024 blocks (4/CU). Block = 16 rows x 4096 cands. Thread (r = lane&15, g = w*4+(lane>>4))
// scans 256 candidates, keeps sorted top-20 as 20 NAMED u64 registers:
// key = monotonic-bits(f64 dist) with low 12 bits = 4095-j  (index rides in the key).
// asm anchors pin the 20 u64s into VGPR pairs at every loop back-edge so the
// allocator cannot sink the list to scratch (r3 failure mode: 34.8 GB scratch writes).

__device__ __forceinline__ unsigned long long packkey(double d, int j) {
    unsigned long long u = __double_as_longlong(d);
    u ^= (unsigned long long)((long long)u >> 63) | 0x8000000000000000ULL;
    return (u & ~0xFFFULL) | (unsigned long long)(4095 - j);
}

#define LIST20(M) M(0) M(1) M(2) M(3) M(4) M(5) M(6) M(7) M(8) M(9) \
                  M(10) M(11) M(12) M(13) M(14) M(15) M(16) M(17) M(18) M(19)

#define CSW(A,B) { if (K##A > K##B) { unsigned long long _t = K##A; K##A = K##B; K##B = _t; } }
#define INS20(k) do { K0 = (k); \
    CSW(0,1) CSW(1,2) CSW(2,3) CSW(3,4) CSW(4,5) CSW(5,6) CSW(6,7) CSW(7,8) CSW(8,9) CSW(9,10) \
    CSW(10,11) CSW(11,12) CSW(12,13) CSW(13,14) CSW(14,15) CSW(15,16) CSW(16,17) CSW(17,18) CSW(18,19) \
} while (0)

#define ANCHOR20() asm volatile("" : \
    "+v"(K0),"+v"(K1),"+v"(K2),"+v"(K3),"+v"(K4),"+v"(K5),"+v"(K6),"+v"(K7),"+v"(K8),"+v"(K9), \
    "+v"(K10),"+v"(K11),"+v"(K12),"+v"(K13),"+v"(K14),"+v"(K15),"+v"(K16),"+v"(K17),"+v"(K18),"+v"(K19))

__global__ __launch_bounds__(256, 4) __attribute__((amdgpu_waves_per_eu(4, 4)))
void knn_kernel(const float* __restrict__ x, const double* __restrict__ xx,
                int* __restrict__ idxOut) {
    __shared__ __align__(16) char smem[37376];
    float  (*rowT)[16]  = (float(*)[16])smem;              // [64][16] f32   4096 B
    double (*candT)[64] = (double(*)[64])(smem + 4096);    // [64][64] f64  32768 B
    double *xxc         = (double*)(smem + 4096 + 32768);  // [64]           512 B
    // merge-phase alias (stage buffers dead by then):
    unsigned long long (*mK)[KK] = (unsigned long long(*)[KK])smem;  // [128][20] 20480 B

    int tid  = threadIdx.x;
    int lane = tid & 63, w = tid >> 6;
    int r = lane & 15;                // row within block
    int g = w * 4 + (lane >> 4);      // candidate group 0..15
    int b  = blockIdx.x >> 8;
    int r0 = (blockIdx.x & 255) * 16;
    const float* xb = x + (size_t)b * CC * NNN;

    for (int i = tid; i < CC * 16; i += 256) {
        int c = i >> 4, rr = i & 15;
        rowT[c][rr] = xb[(size_t)c * NNN + r0 + rr];
    }
    double xr = xx[b * NNN + r0 + r];

    unsigned long long K0=0,K1=0,K2=0,K3=0,K4=0,K5=0,K6=0,K7=0,K8=0,K9=0,
                       K10=0,K11=0,K12=0,K13=0,K14=0,K15=0,K16=0,K17=0,K18=0,K19=0;
    ANCHOR20();

    for (int j0 = 0; j0 < NNN; j0 += 64) {
        __syncthreads();                       // candT readers of prev tile done
        for (int i = tid; i < CC * 64; i += 256) {
            int c = i >> 6, jj = i & 63;
            candT[c][jj] = (double)xb[(size_t)c * NNN + j0 + jj];
        }
        if (tid < 64) xxc[tid] = xx[b * NNN + j0 + tid];
        __syncthreads();
        double a0 = 0.0, a1 = 0.0, a2 = 0.0, a3 = 0.0;
        for (int c = 0; c < CC; ++c) {
            double rv = (double)rowT[c][r];
            double2 c01 = *(const double2*)&candT[c][g * 4];
            double2 c23 = *(const double2*)&candT[c][g * 4 + 2];
            a0 = fma(rv, c01.x, a0);
            a1 = fma(rv, c01.y, a1);
            a2 = fma(rv, c23.x, a2);
            a3 = fma(rv, c23.y, a3);
        }
        {
            double d; unsigned long long k;
            d = 2.0 * a0 - xr - xxc[g * 4 + 0]; k = packkey(d, j0 + g * 4 + 0); if (k > K0) INS20(k);
            d = 2.0 * a1 - xr - xxc[g * 4 + 1]; k = packkey(d, j0 + g * 4 + 1); if (k > K0) INS20(k);
            d = 2.0 * a2 - xr - xxc[g * 4 + 2]; k = packkey(d, j0 + g * 4 + 2); if (k > K0) INS20(k);
            d = 2.0 * a3 - xr - xxc[g * 4 + 3]; k = packkey(d, j0 + g * 4 + 3); if (k > K0) INS20(k);
        }
        ANCHOR20();                            // pin list in VGPRs across the back-edge
    }

    // merge tree: step s, groups that are multiples of 2^s pair up; odd half publishes.
    for (int s = 0; s < 4; ++s) {
        __syncthreads();                       // also protects smem alias on s=0
        int bit = 1 << s;
        bool alive = (g & (bit - 1)) == 0;
        bool pub = alive && (g & bit);
        int slot = (g >> (s + 1)) * 16 + r;    // same for publisher and its merger
        if (pub) {
            #define PUBQ(Q) mK[slot][Q] = K##Q;
            LIST20(PUBQ)
            #undef PUBQ
        }
        __syncthreads();
        if (alive && !pub) {
            for (int q = KK - 1; q >= 0; --q) {          // partner sorted asc: scan from best
                unsigned long long pk = mK[slot][q];
                if (pk <= K0) break;
                INS20(pk);
            }
        }
        ANCHOR20();
    }
    if (g == 0) {
        int* op = idxOut + ((size_t)b * NNN + r0 + r) * KK;
        #define OUTQ(Q) op[Q] = 4095 - (int)(K##Q & 0xFFFULL);
        LIST20(OUTQ)
        #undef OUTQ
    }
}

// ---------------- K4: h1 = relu(bn1(A[nb]+Bv[n])); h2 = relu(bn2(h1·w2^T)); max over k ----------------
__global__ __launch_bounds__(256) void edge_kernel(const float* __restrict__ A, const float* __restrict__ Bv,
        const int* __restrict__ idx, const float* __restrict__ w2,
        const float* __restrict__ g1, const float* __restrict__ be1, const float* __restrict__ m1, const float* __restrict__ v1,
        const float* __restrict__ g2, const float* __restrict__ be2, const float* __restrict__ m2, const float* __restrict__ v2,
        float* __restrict__ out) {
    __shared__ float h1buf[4][KK][64];
    __shared__ float resT[64][33];
    int tid = threadIdx.x;
    int lane = tid & 63, w = tid >> 6;
    int b = blockIdx.x >> 7;
    int n0 = (blockIdx.x & 127) * 32;
    float s1 = g1[lane] * rsqrtf(v1[lane] + EPSF);
    float bb1 = be1[lane] - m1[lane] * s1;
    float s2 = g2[lane] * rsqrtf(v2[lane] + EPSF);
    float bb2 = be2[lane] - m2[lane] * s2;
    float w2r[64];
    #pragma unroll
    for (int o = 0; o < 64; ++o) w2r[o] = w2[lane * 64 + o];
    for (int p = 0; p < 8; ++p) {
        int n = n0 + w * 8 + p;
        size_t pb = (size_t)b * NNN + n;
        float bv = Bv[pb * 64 + lane];
        const int* ip = idx + pb * KK;
        #pragma unroll
        for (int k = 0; k < KK; ++k) {
            int nb = ip[k];
            float av = A[((size_t)b * NNN + nb) * 64 + lane];
            h1buf[w][k][lane] = fmaxf(0.f, fmaf(av + bv, s1, bb1));
        }
        __syncthreads();
        float mx = -1e30f;
        for (int k = 0; k < KK; ++k) {
            const float4* hb = (const float4*)&h1buf[w][k][0];
            float dot = 0.f;
            #pragma unroll
            for (int o4 = 0; o4 < 16; ++o4) {
                float4 h = hb[o4];
                dot = fmaf(w2r[o4 * 4 + 0], h.x, dot);
                dot = fmaf(w2r[o4 * 4 + 1], h.y, dot);
                dot = fmaf(w2r[o4 * 4 + 2], h.z, dot);
                dot = fmaf(w2r[o4 * 4 + 3], h.w, dot);
            }
            mx = fmaxf(mx, fmaxf(0.f, fmaf(dot, s2, bb2)));
        }
        resT[lane][w * 8 + p] = mx;
        __syncthreads();
    }
    for (int i = tid; i < 64 * 32; i += 256) {
        int o2 = i >> 5, pp = i & 31;
        out[((size_t)b * 64 + o2) * NNN + n0 + pp] = resT[o2][pp];
    }
}

extern "C" void kernel_launch(void* const* d_in, const int* in_sizes, int n_in,
                              void* d_out, int out_size, void* d_ws, size_t ws_size,
                              hipStream_t stream) {
    const float* x   = (const float*)d_in[0];
    const float* w1  = (const float*)d_in[1];
    const float* g1  = (const float*)d_in[2];
    const float* be1 = (const float*)d_in[3];
    const float* m1  = (const float*)d_in[4];
    const float* v1  = (const float*)d_in[5];
    const float* w2  = (const float*)d_in[6];
    const float* g2  = (const float*)d_in[7];
    const float* be2 = (const float*)d_in[8];
    const float* m2  = (const float*)d_in[9];
    const float* v2  = (const float*)d_in[10];
    // ws layout: xx f64 (128KB) | A f32 (4MB) | Bv f32 (4MB) | idx i32 (1.25MB)
    char* ws = (char*)d_ws;
    double* xx = (double*)ws;
    float*  A  = (float*)(ws + 131072);
    float*  Bv = (float*)(ws + 131072 + 4194304);
    int*    nidx = (int*)(ws + 131072 + 2 * 4194304);
    float*  out = (float*)d_out;

    hipLaunchKernelGGL(xx_kernel,   dim3(BB * NNN / 256), dim3(256), 0, stream, x, xx);
    hipLaunchKernelGGL(proj_kernel, dim3(BB * (NNN / 64)), dim3(256), 0, stream, x, w1, A, Bv);
    hipLaunchKernelGGL(knn_kernel,  dim3(BB * (NNN / 16)), dim3(256), 0, stream, x, xx, nidx);
    hipLaunchKernelGGL(edge_kernel, dim3(BB * (NNN / 32)), dim3(256), 0, stream,
                       A, Bv, nidx, w2, g1, be1, m1, v1, g2, be2, m2, v2, out);
}

// Round 5
// 19940.631 us; speedup vs baseline: 1.0074x; 1.0074x over previous
//
#include <hip/hip_runtime.h>

#define BB 4
#define CC 64
#define NNN 4096
#define OO 64
#define KK 20
#define EPSF 1e-5f

// ---------------- K1: xx[n] = sum_c x[c][n]^2 in f64 ----------------
__global__ __launch_bounds__(256) void xx_kernel(const float* __restrict__ x, double* __restrict__ xx) {
    int g = blockIdx.x * 256 + threadIdx.x;          // 0..B*N-1
    int b = g >> 12, n = g & (NNN - 1);
    const float* xp = x + (size_t)b * CC * NNN + n;
    double s = 0.0;
    for (int c = 0; c < CC; ++c) {
        double v = (double)xp[(size_t)c * NNN];
        s += v * v;
    }
    xx[g] = s;
}

// ---------------- K2: per-point projections A = x*w1a^T, Bv = x*(w1b-w1a)^T ----------------
__global__ __launch_bounds__(256) void proj_kernel(const float* __restrict__ x, const float* __restrict__ w1,
                                                   float* __restrict__ A, float* __restrict__ Bv) {
    __shared__ float xs[CC][64];       // [c][p]
    __shared__ float ws1[OO][129];     // padded
    int tid = threadIdx.x;
    int b = blockIdx.x >> 6;
    int p0 = (blockIdx.x & 63) << 6;
    const float* xb = x + (size_t)b * CC * NNN;
    for (int i = tid; i < CC * 16; i += 256) {
        int c = i >> 4, q = i & 15;
        *(float4*)&xs[c][q * 4] = *(const float4*)(xb + (size_t)c * NNN + p0 + q * 4);
    }
    for (int i = tid; i < OO * 32; i += 256) {
        int o = i >> 5, q = i & 31;
        float4 v = *(const float4*)(w1 + o * 128 + q * 4);
        ws1[o][q * 4 + 0] = v.x; ws1[o][q * 4 + 1] = v.y;
        ws1[o][q * 4 + 2] = v.z; ws1[o][q * 4 + 3] = v.w;
    }
    __syncthreads();
    int ti = tid >> 4, tj = tid & 15;
    float aA[4][4] = {{0.f}}, aD[4][4] = {{0.f}};
    for (int c = 0; c < CC; ++c) {
        float4 xv4 = *(const float4*)&xs[c][ti * 4];
        float xv[4] = {xv4.x, xv4.y, xv4.z, xv4.w};
        #pragma unroll
        for (int oo = 0; oo < 4; ++oo) {
            float wa = ws1[tj * 4 + oo][c];
            float wd = ws1[tj * 4 + oo][64 + c] - wa;
            #pragma unroll
            for (int pp = 0; pp < 4; ++pp) {
                aA[pp][oo] = fmaf(xv[pp], wa, aA[pp][oo]);
                aD[pp][oo] = fmaf(xv[pp], wd, aD[pp][oo]);
            }
        }
    }
    size_t base = ((size_t)b * NNN + p0) * 64;
    #pragma unroll
    for (int pp = 0; pp < 4; ++pp) {
        int p = ti * 4 + pp;
        *(float4*)(A  + base + (size_t)p * 64 + tj * 4) = make_float4(aA[pp][0], aA[pp][1], aA[pp][2], aA[pp][3]);
        *(float4*)(Bv + base + (size_t)p * 64 + tj * 4) = make_float4(aD[pp][0], aD[pp][1], aD[pp][2], aD[pp][3]);
    }
}

// ---------------- K3: f64 distances + wave-distributed top-20 (1 VGPR-pair/lane/row) ----------------
// 1024 blocks (4/CU by LDS: 40960 B). Block = 16 rows; wave w owns rows w*4..w*4+3.
// Per 64-cand tile: lane j computes cand j's distance to the wave's 4 rows (4 f64 accs).
// Row list: lane e<20 holds entry e (u64 key = monotonic f64 | (4095-idx)) in a register.
// Insert: ballot -> serialize bits -> shfl-broadcast -> min-lane replaces -> shfl argmin
// rebuilds (T, minLane). No per-thread arrays, no scratch possible (~50 VGPR live).

__device__ __forceinline__ unsigned long long packkey(double d, int j) {
    unsigned long long u = __double_as_longlong(d);
    u ^= (unsigned long long)((long long)u >> 63) | 0x8000000000000000ULL;
    return (u & ~0xFFFULL) | (unsigned long long)(4095 - j);
}

__device__ __forceinline__ void argminU64(unsigned long long &v, int &li) {
    #pragma unroll
    for (int off = 1; off < 64; off <<= 1) {
        unsigned long long ov = __shfl_xor(v, off);
        int oi = __shfl_xor(li, off);
        if (ov < v || (ov == v && oi < li)) { v = ov; li = oi; }
    }
}

__device__ __forceinline__ void argmaxU64(unsigned long long &v, int &li) {
    #pragma unroll
    for (int off = 1; off < 64; off <<= 1) {
        unsigned long long ov = __shfl_xor(v, off);
        int oi = __shfl_xor(li, off);
        if (ov > v || (ov == v && oi < li)) { v = ov; li = oi; }
    }
}

__global__ __launch_bounds__(256, 4) void knn_kernel(const float* __restrict__ x, const double* __restrict__ xx,
                                                     int* __restrict__ idxOut) {
    __shared__ double candT[CC][64];   // 32768 B, per-lane b64 stride-8B = 2-way (free)
    __shared__ double rowT[CC][16];    // 8192 B; total 40960 = 160K/4 -> 4 blocks/CU
    int tid = threadIdx.x;
    int lane = tid & 63, w = tid >> 6;
    int b = blockIdx.x >> 8;
    int r0 = (blockIdx.x & 255) * 16;
    const float* xb = x + (size_t)b * CC * NNN;

    for (int i = tid; i < CC * 16; i += 256) {
        int c = i >> 4, rr = i & 15;
        rowT[c][rr] = (double)xb[(size_t)c * NNN + r0 + rr];
    }
    double xr[4];
    #pragma unroll
    for (int rl = 0; rl < 4; ++rl) xr[rl] = xx[(size_t)b * NNN + r0 + w * 4 + rl];

    unsigned long long S[4] = {0, 0, 0, 0};   // list entry (valid for lane<20)
    unsigned long long T[4] = {0, 0, 0, 0};   // wave-uniform current min of list
    int mL[4] = {0, 0, 0, 0};                 // wave-uniform lane holding the min

    for (int j0 = 0; j0 < NNN; j0 += 64) {
        __syncthreads();                       // prev tile's readers done
        for (int i = tid; i < CC * 64; i += 256) {
            int c = i >> 6, jj = i & 63;
            candT[c][jj] = (double)xb[(size_t)c * NNN + j0 + jj];
        }
        __syncthreads();
        double a0 = 0.0, a1 = 0.0, a2 = 0.0, a3 = 0.0;
        for (int c = 0; c < CC; ++c) {
            double cd = candT[c][lane];
            double2 ra = *(const double2*)&rowT[c][w * 4];
            double2 rb = *(const double2*)&rowT[c][w * 4 + 2];
            a0 = fma(ra.x, cd, a0);
            a1 = fma(ra.y, cd, a1);
            a2 = fma(rb.x, cd, a2);
            a3 = fma(rb.y, cd, a3);
        }
        double acc[4] = {a0, a1, a2, a3};
        double xq = xx[(size_t)b * NNN + j0 + lane];
        #pragma unroll
        for (int rl = 0; rl < 4; ++rl) {
            double d = 2.0 * acc[rl] - xr[rl] - xq;
            unsigned long long key = packkey(d, j0 + lane);
            unsigned long long m = __ballot(key > T[rl]);
            while (m) {
                int src = (int)__builtin_ctzll(m);
                m &= m - 1;
                unsigned long long kb = __shfl(key, src);
                if (kb > T[rl]) {                      // uniform branch, re-check vs updated T
                    if (lane == mL[rl]) S[rl] = kb;    // replace current min entry
                    unsigned long long v = (lane < KK) ? S[rl] : ~0ULL;
                    int li = lane;
                    argminU64(v, li);                  // all lanes -> uniform (min, argmin)
                    T[rl] = v; mL[rl] = li;
                }
            }
        }
    }

    // extraction: 20 argmax rounds per row, descending (ties impossible: idx in key)
    #pragma unroll
    for (int rl = 0; rl < 4; ++rl) {
        int* op = idxOut + ((size_t)b * NNN + r0 + w * 4 + rl) * KK;
        for (int q = 0; q < KK; ++q) {
            unsigned long long v = (lane < KK) ? S[rl] : 0ULL;
            int li = lane;
            argmaxU64(v, li);
            if (lane == 0) op[q] = 4095 - (int)(v & 0xFFFULL);
            if (lane == li) S[rl] = 0ULL;              // remove extracted entry
        }
    }
}

// ---------------- K4: h1 = relu(bn1(A[nb]+Bv[n])); h2 = relu(bn2(h1·w2^T)); max over k ----------------
__global__ __launch_bounds__(256) void edge_kernel(const float* __restrict__ A, const float* __restrict__ Bv,
        const int* __restrict__ idx, const float* __restrict__ w2,
        const float* __restrict__ g1, const float* __restrict__ be1, const float* __restrict__ m1, const float* __restrict__ v1,
        const float* __restrict__ g2, const float* __restrict__ be2, const float* __restrict__ m2, const float* __restrict__ v2,
        float* __restrict__ out) {
    __shared__ float h1buf[4][KK][64];
    __shared__ float resT[64][33];
    int tid = threadIdx.x;
    int lane = tid & 63, w = tid >> 6;
    int b = blockIdx.x >> 7;
    int n0 = (blockIdx.x & 127) * 32;
    float s1 = g1[lane] * rsqrtf(v1[lane] + EPSF);
    float bb1 = be1[lane] - m1[lane] * s1;
    float s2 = g2[lane] * rsqrtf(v2[lane] + EPSF);
    float bb2 = be2[lane] - m2[lane] * s2;
    float w2r[64];
    #pragma unroll
    for (int o = 0; o < 64; ++o) w2r[o] = w2[lane * 64 + o];
    for (int p = 0; p < 8; ++p) {
        int n = n0 + w * 8 + p;
        size_t pb = (size_t)b * NNN + n;
        float bv = Bv[pb * 64 + lane];
        const int* ip = idx + pb * KK;
        #pragma unroll
        for (int k = 0; k < KK; ++k) {
            int nb = ip[k];
            float av = A[((size_t)b * NNN + nb) * 64 + lane];
            h1buf[w][k][lane] = fmaxf(0.f, fmaf(av + bv, s1, bb1));
        }
        __syncthreads();
        float mx = -1e30f;
        for (int k = 0; k < KK; ++k) {
            const float4* hb = (const float4*)&h1buf[w][k][0];
            float dot = 0.f;
            #pragma unroll
            for (int o4 = 0; o4 < 16; ++o4) {
                float4 h = hb[o4];
                dot = fmaf(w2r[o4 * 4 + 0], h.x, dot);
                dot = fmaf(w2r[o4 * 4 + 1], h.y, dot);
                dot = fmaf(w2r[o4 * 4 + 2], h.z, dot);
                dot = fmaf(w2r[o4 * 4 + 3], h.w, dot);
            }
            mx = fmaxf(mx, fmaxf(0.f, fmaf(dot, s2, bb2)));
        }
        resT[lane][w * 8 + p] = mx;
        __syncthreads();
    }
    for (int i = tid; i < 64 * 32; i += 256) {
        int o2 = i >> 5, pp = i & 31;
        out[((size_t)b * 64 + o2) * NNN + n0 + pp] = resT[o2][pp];
    }
}

extern "C" void kernel_launch(void* const* d_in, const int* in_sizes, int n_in,
                              void* d_out, int out_size, void* d_ws, size_t ws_size,
                              hipStream_t stream) {
    const float* x   = (const float*)d_in[0];
    const float* w1  = (const float*)d_in[1];
    const float* g1  = (const float*)d_in[2];
    const float* be1 = (const float*)d_in[3];
    const float* m1  = (const float*)d_in[4];
    const float* v1  = (const float*)d_in[5];
    const float* w2  = (const float*)d_in[6];
    const float* g2  = (const float*)d_in[7];
    const float* be2 = (const float*)d_in[8];
    const float* m2  = (const float*)d_in[9];
    const float* v2  = (const float*)d_in[10];
    // ws layout: xx f64 (128KB) | A f32 (4MB) | Bv f32 (4MB) | idx i32 (1.25MB)
    char* ws = (char*)d_ws;
    double* xx = (double*)ws;
    float*  A  = (float*)(ws + 131072);
    float*  Bv = (float*)(ws + 131072 + 4194304);
    int*    nidx = (int*)(ws + 131072 + 2 * 4194304);
    float*  out = (float*)d_out;

    hipLaunchKernelGGL(xx_kernel,   dim3(BB * NNN / 256), dim3(256), 0, stream, x, xx);
    hipLaunchKernelGGL(proj_kernel, dim3(BB * (NNN / 64)), dim3(256), 0, stream, x, w1, A, Bv);
    hipLaunchKernelGGL(knn_kernel,  dim3(BB * (NNN / 16)), dim3(256), 0, stream, x, xx, nidx);
    hipLaunchKernelGGL(edge_kernel, dim3(BB * (NNN / 32)), dim3(256), 0, stream,
                       A, Bv, nidx, w2, g1, be1, m1, v1, g2, be2, m2, v2, out);
}

// Round 6
// 3733.784 us; speedup vs baseline: 5.3802x; 5.3406x over previous
//
#include <hip/hip_runtime.h>

#define BB 4
#define CC 64
#define NNN 4096
#define OO 64
#define KK 20
#define EPSF 1e-5f

// ---------------- K1: xx[n] = sum_c x[c][n]^2 in f64 ----------------
__global__ __launch_bounds__(256) void xx_kernel(const float* __restrict__ x, double* __restrict__ xx) {
    int g = blockIdx.x * 256 + threadIdx.x;          // 0..B*N-1
    int b = g >> 12, n = g & (NNN - 1);
    const float* xp = x + (size_t)b * CC * NNN + n;
    double s = 0.0;
    for (int c = 0; c < CC; ++c) {
        double v = (double)xp[(size_t)c * NNN];
        s += v * v;
    }
    xx[g] = s;
}

// ---------------- K2: per-point projections A = x*w1a^T, Bv = x*(w1b-w1a)^T ----------------
__global__ __launch_bounds__(256) void proj_kernel(const float* __restrict__ x, const float* __restrict__ w1,
                                                   float* __restrict__ A, float* __restrict__ Bv) {
    __shared__ float xs[CC][64];       // [c][p]
    __shared__ float ws1[OO][129];     // padded
    int tid = threadIdx.x;
    int b = blockIdx.x >> 6;
    int p0 = (blockIdx.x & 63) << 6;
    const float* xb = x + (size_t)b * CC * NNN;
    for (int i = tid; i < CC * 16; i += 256) {
        int c = i >> 4, q = i & 15;
        *(float4*)&xs[c][q * 4] = *(const float4*)(xb + (size_t)c * NNN + p0 + q * 4);
    }
    for (int i = tid; i < OO * 32; i += 256) {
        int o = i >> 5, q = i & 31;
        float4 v = *(const float4*)(w1 + o * 128 + q * 4);
        ws1[o][q * 4 + 0] = v.x; ws1[o][q * 4 + 1] = v.y;
        ws1[o][q * 4 + 2] = v.z; ws1[o][q * 4 + 3] = v.w;
    }
    __syncthreads();
    int ti = tid >> 4, tj = tid & 15;
    float aA[4][4] = {{0.f}}, aD[4][4] = {{0.f}};
    for (int c = 0; c < CC; ++c) {
        float4 xv4 = *(const float4*)&xs[c][ti * 4];
        float xv[4] = {xv4.x, xv4.y, xv4.z, xv4.w};
        #pragma unroll
        for (int oo = 0; oo < 4; ++oo) {
            float wa = ws1[tj * 4 + oo][c];
            float wd = ws1[tj * 4 + oo][64 + c] - wa;
            #pragma unroll
            for (int pp = 0; pp < 4; ++pp) {
                aA[pp][oo] = fmaf(xv[pp], wa, aA[pp][oo]);
                aD[pp][oo] = fmaf(xv[pp], wd, aD[pp][oo]);
            }
        }
    }
    size_t base = ((size_t)b * NNN + p0) * 64;
    #pragma unroll
    for (int pp = 0; pp < 4; ++pp) {
        int p = ti * 4 + pp;
        *(float4*)(A  + base + (size_t)p * 64 + tj * 4) = make_float4(aA[pp][0], aA[pp][1], aA[pp][2], aA[pp][3]);
        *(float4*)(Bv + base + (size_t)p * 64 + tj * 4) = make_float4(aD[pp][0], aD[pp][1], aD[pp][2], aD[pp][3]);
    }
}

// ---------------- K3: r1-structure knn, rebalanced ----------------
// 1024 blocks (3/CU by LDS: 53248 B). Block = 16 rows x 4096 cands, 64-cand tiles.
// Thread (r = tid&15, jg = tid>>4) computes cands jg*4..+3 vs row r in f64 (pure
// fma_f64 on LDS-f64 broadcast reads; conversion done once at staging).
// Selection: threads 0..15 (one per row) run r1's exact LDS-list insert scan.
// NO per-thread arrays anywhere; lists live in LDS. Plain __launch_bounds__(256).
__global__ __launch_bounds__(256) void knn_kernel(const float* __restrict__ x, const double* __restrict__ xx,
                                                  int* __restrict__ idxOut) {
    __shared__ double rowT[CC][16];    //  8192 B
    __shared__ double candT[CC][64];   // 32768 B
    __shared__ double distT[16][65];   //  8320 B (pad 65: conflict-light)
    __shared__ double listD[16][KK];   //  2560 B
    __shared__ int    listI[16][KK];   //  1280 B
    __shared__ double xxr[16];         //   128 B   -> total 53248 B = 3 blocks/CU
    int tid = threadIdx.x;
    int b  = blockIdx.x >> 8;
    int r0 = (blockIdx.x & 255) * 16;
    const float* xb = x + (size_t)b * CC * NNN;

    for (int i = tid; i < CC * 16; i += 256) {
        int c = i >> 4, rr = i & 15;
        rowT[c][rr] = (double)xb[(size_t)c * NNN + r0 + rr];
    }
    if (tid < 16) {
        xxr[tid] = xx[(size_t)b * NNN + r0 + tid];
        for (int q = 0; q < KK; ++q) { listD[tid][q] = -1.0e300; listI[tid][q] = 0x7fffffff; }
    }
    int r = tid & 15, jg = tid >> 4;
    double mv = -1.0e300; int mp = 0, mIdx = 0x7fffffff;   // selection regs (tid<16)

    for (int j0 = 0; j0 < NNN; j0 += 64) {
        __syncthreads();                       // A: select(t-1) done; compute(t-1) candT reads done
        for (int i = tid; i < CC * 64; i += 256) {
            int c = i >> 6, jj = i & 63;
            candT[c][jj] = (double)xb[(size_t)c * NNN + j0 + jj];
        }
        __syncthreads();                       // B: candT ready
        double a0 = 0.0, a1 = 0.0, a2 = 0.0, a3 = 0.0;
        for (int c = 0; c < CC; ++c) {
            double rv = rowT[c][r];                            // 4-way broadcast
            double2 cA = *(const double2*)&candT[c][jg * 4];   // 16-way broadcast
            double2 cB = *(const double2*)&candT[c][jg * 4 + 2];
            a0 = fma(rv, cA.x, a0);
            a1 = fma(rv, cA.y, a1);
            a2 = fma(rv, cB.x, a2);
            a3 = fma(rv, cB.y, a3);
        }
        {   // d = 2*acc - xx[row] - xx[cand]; xq loaded direct (L2-broadcast)
            double xr2 = xxr[r];
            const double* xq = xx + (size_t)b * NNN + j0 + jg * 4;
            distT[r][jg * 4 + 0] = 2.0 * a0 - xr2 - xq[0];
            distT[r][jg * 4 + 1] = 2.0 * a1 - xr2 - xq[1];
            distT[r][jg * 4 + 2] = 2.0 * a2 - xr2 - xq[2];
            distT[r][jg * 4 + 3] = 2.0 * a3 - xr2 - xq[3];
        }
        __syncthreads();                       // C: distT ready
        if (tid < 16) {                        // r1's exact selection logic
            for (int j = 0; j < 64; ++j) {
                double d = distT[tid][j];
                int jgl = j0 + j;
                if (d > mv || (d == mv && jgl < mIdx)) {
                    listD[tid][mp] = d; listI[tid][mp] = jgl;
                    mv = listD[tid][0]; mIdx = listI[tid][0]; mp = 0;
                    for (int q = 1; q < KK; ++q) {
                        double dq = listD[tid][q]; int iq = listI[tid][q];
                        if (dq < mv || (dq == mv && iq > mIdx)) { mv = dq; mIdx = iq; mp = q; }
                    }
                }
            }
        }
    }
    if (tid < 16) {
        for (int q = 0; q < KK; ++q)
            idxOut[((size_t)b * NNN + r0 + tid) * KK + q] = listI[tid][q];
    }
}

// ---------------- K4: h1 = relu(bn1(A[nb]+Bv[n])); h2 = relu(bn2(h1·w2^T)); max over k ----------------
__global__ __launch_bounds__(256) void edge_kernel(const float* __restrict__ A, const float* __restrict__ Bv,
        const int* __restrict__ idx, const float* __restrict__ w2,
        const float* __restrict__ g1, const float* __restrict__ be1, const float* __restrict__ m1, const float* __restrict__ v1,
        const float* __restrict__ g2, const float* __restrict__ be2, const float* __restrict__ m2, const float* __restrict__ v2,
        float* __restrict__ out) {
    __shared__ float h1buf[4][KK][64];
    __shared__ float resT[64][33];
    int tid = threadIdx.x;
    int lane = tid & 63, w = tid >> 6;
    int b = blockIdx.x >> 7;
    int n0 = (blockIdx.x & 127) * 32;
    float s1 = g1[lane] * rsqrtf(v1[lane] + EPSF);
    float bb1 = be1[lane] - m1[lane] * s1;
    float s2 = g2[lane] * rsqrtf(v2[lane] + EPSF);
    float bb2 = be2[lane] - m2[lane] * s2;
    float w2r[64];
    #pragma unroll
    for (int o = 0; o < 64; ++o) w2r[o] = w2[lane * 64 + o];
    for (int p = 0; p < 8; ++p) {
        int n = n0 + w * 8 + p;
        size_t pb = (size_t)b * NNN + n;
        float bv = Bv[pb * 64 + lane];
        const int* ip = idx + pb * KK;
        #pragma unroll
        for (int k = 0; k < KK; ++k) {
            int nb = ip[k];
            float av = A[((size_t)b * NNN + nb) * 64 + lane];
            h1buf[w][k][lane] = fmaxf(0.f, fmaf(av + bv, s1, bb1));
        }
        __syncthreads();
        float mx = -1e30f;
        for (int k = 0; k < KK; ++k) {
            const float4* hb = (const float4*)&h1buf[w][k][0];
            float dot = 0.f;
            #pragma unroll
            for (int o4 = 0; o4 < 16; ++o4) {
                float4 h = hb[o4];
                dot = fmaf(w2r[o4 * 4 + 0], h.x, dot);
                dot = fmaf(w2r[o4 * 4 + 1], h.y, dot);
                dot = fmaf(w2r[o4 * 4 + 2], h.z, dot);
                dot = fmaf(w2r[o4 * 4 + 3], h.w, dot);
            }
            mx = fmaxf(mx, fmaxf(0.f, fmaf(dot, s2, bb2)));
        }
        resT[lane][w * 8 + p] = mx;
        __syncthreads();
    }
    for (int i = tid; i < 64 * 32; i += 256) {
        int o2 = i >> 5, pp = i & 31;
        out[((size_t)b * 64 + o2) * NNN + n0 + pp] = resT[o2][pp];
    }
}

extern "C" void kernel_launch(void* const* d_in, const int* in_sizes, int n_in,
                              void* d_out, int out_size, void* d_ws, size_t ws_size,
                              hipStream_t stream) {
    const float* x   = (const float*)d_in[0];
    const float* w1  = (const float*)d_in[1];
    const float* g1  = (const float*)d_in[2];
    const float* be1 = (const float*)d_in[3];
    const float* m1  = (const float*)d_in[4];
    const float* v1  = (const float*)d_in[5];
    const float* w2  = (const float*)d_in[6];
    const float* g2  = (const float*)d_in[7];
    const float* be2 = (const float*)d_in[8];
    const float* m2  = (const float*)d_in[9];
    const float* v2  = (const float*)d_in[10];
    // ws layout: xx f64 (128KB) | A f32 (4MB) | Bv f32 (4MB) | idx i32 (1.25MB)
    char* ws = (char*)d_ws;
    double* xx = (double*)ws;
    float*  A  = (float*)(ws + 131072);
    float*  Bv = (float*)(ws + 131072 + 4194304);
    int*    nidx = (int*)(ws + 131072 + 2 * 4194304);
    float*  out = (float*)d_out;

    hipLaunchKernelGGL(xx_kernel,   dim3(BB * NNN / 256), dim3(256), 0, stream, x, xx);
    hipLaunchKernelGGL(proj_kernel, dim3(BB * (NNN / 64)), dim3(256), 0, stream, x, w1, A, Bv);
    hipLaunchKernelGGL(knn_kernel,  dim3(BB * (NNN / 16)), dim3(256), 0, stream, x, xx, nidx);
    hipLaunchKernelGGL(edge_kernel, dim3(BB * (NNN / 32)), dim3(256), 0, stream,
                       A, Bv, nidx, w2, g1, be1, m1, v1, g2, be2, m2, v2, out);
}

// Round 7
// 1072.955 us; speedup vs baseline: 18.7226x; 3.4799x over previous
//
#include <hip/hip_runtime.h>

#define BB 4
#define CC 64
#define NNN 4096
#define OO 64
#define KK 20
#define EPSF 1e-5f

// ---------------- K1: xx[n] = sum_c x[c][n]^2 in f64 ----------------
__global__ __launch_bounds__(256) void xx_kernel(const float* __restrict__ x, double* __restrict__ xx) {
    int g = blockIdx.x * 256 + threadIdx.x;          // 0..B*N-1
    int b = g >> 12, n = g & (NNN - 1);
    const float* xp = x + (size_t)b * CC * NNN + n;
    double s = 0.0;
    for (int c = 0; c < CC; ++c) {
        double v = (double)xp[(size_t)c * NNN];
        s += v * v;
    }
    xx[g] = s;
}

// ---------------- K2: per-point projections A = x*w1a^T, Bv = x*(w1b-w1a)^T ----------------
__global__ __launch_bounds__(256) void proj_kernel(const float* __restrict__ x, const float* __restrict__ w1,
                                                   float* __restrict__ A, float* __restrict__ Bv) {
    __shared__ float xs[CC][64];       // [c][p]
    __shared__ float ws1[OO][129];     // padded
    int tid = threadIdx.x;
    int b = blockIdx.x >> 6;
    int p0 = (blockIdx.x & 63) << 6;
    const float* xb = x + (size_t)b * CC * NNN;
    for (int i = tid; i < CC * 16; i += 256) {
        int c = i >> 4, q = i & 15;
        *(float4*)&xs[c][q * 4] = *(const float4*)(xb + (size_t)c * NNN + p0 + q * 4);
    }
    for (int i = tid; i < OO * 32; i += 256) {
        int o = i >> 5, q = i & 31;
        float4 v = *(const float4*)(w1 + o * 128 + q * 4);
        ws1[o][q * 4 + 0] = v.x; ws1[o][q * 4 + 1] = v.y;
        ws1[o][q * 4 + 2] = v.z; ws1[o][q * 4 + 3] = v.w;
    }
    __syncthreads();
    int ti = tid >> 4, tj = tid & 15;
    float aA[4][4] = {{0.f}}, aD[4][4] = {{0.f}};
    for (int c = 0; c < CC; ++c) {
        float4 xv4 = *(const float4*)&xs[c][ti * 4];
        float xv[4] = {xv4.x, xv4.y, xv4.z, xv4.w};
        #pragma unroll
        for (int oo = 0; oo < 4; ++oo) {
            float wa = ws1[tj * 4 + oo][c];
            float wd = ws1[tj * 4 + oo][64 + c] - wa;
            #pragma unroll
            for (int pp = 0; pp < 4; ++pp) {
                aA[pp][oo] = fmaf(xv[pp], wa, aA[pp][oo]);
                aD[pp][oo] = fmaf(xv[pp], wd, aD[pp][oo]);
            }
        }
    }
    size_t base = ((size_t)b * NNN + p0) * 64;
    #pragma unroll
    for (int pp = 0; pp < 4; ++pp) {
        int p = ti * 4 + pp;
        *(float4*)(A  + base + (size_t)p * 64 + tj * 4) = make_float4(aA[pp][0], aA[pp][1], aA[pp][2], aA[pp][3]);
        *(float4*)(Bv + base + (size_t)p * 64 + tj * 4) = make_float4(aD[pp][0], aD[pp][1], aD[pp][2], aD[pp][3]);
    }
}

// ---------------- K3: f64 distances + wave-parallel sorted-lane top-20 ----------------
// r6 skeleton (1024 blocks, 3/CU, 16 rows x 64-cand tiles, identical f64 fma chain).
// Compute threads write packed u64 keys to distK. Selection: wave w owns rows
// 4w..4w+3; list = lanes 0..19 sorted ascending (named S0..S3, no arrays);
// insert = shfl broadcast + branchless lane shift-insert; no LDS rescans.

__device__ __forceinline__ unsigned long long packkey(double d, int j) {
    unsigned long long u = __double_as_longlong(d);
    u ^= (unsigned long long)((long long)u >> 63) | 0x8000000000000000ULL;
    return (u & ~0xFFFULL) | (unsigned long long)(4095 - j);
}

__global__ __launch_bounds__(256) void knn_kernel(const float* __restrict__ x, const double* __restrict__ xx,
                                                  int* __restrict__ idxOut) {
    __shared__ double rowT[CC][16];              //  8192 B
    __shared__ double candT[CC][64];             // 32768 B
    __shared__ unsigned long long distK[16][65]; //  8320 B (pad 65)
    __shared__ double xxr[16];                   //   128 B  -> 49408 B = 3 blocks/CU
    int tid = threadIdx.x;
    int lane = tid & 63, w = tid >> 6;
    int b  = blockIdx.x >> 8;
    int r0 = (blockIdx.x & 255) * 16;
    const float* xb = x + (size_t)b * CC * NNN;

    for (int i = tid; i < CC * 16; i += 256) {
        int c = i >> 4, rr = i & 15;
        rowT[c][rr] = (double)xb[(size_t)c * NNN + r0 + rr];
    }
    if (tid < 16) xxr[tid] = xx[(size_t)b * NNN + r0 + tid];
    int r = tid & 15, jg = tid >> 4;

    // per-wave sorted lists (lane-distributed; ascending; lanes>=20 pinned at ~0)
    unsigned long long S0, S1, S2, S3;
    S0 = S1 = S2 = S3 = (lane < KK) ? 0ULL : ~0ULL;
    unsigned long long T0 = 0, T1 = 0, T2 = 0, T3 = 0;   // wave-uniform list minima

    for (int j0 = 0; j0 < NNN; j0 += 64) {
        __syncthreads();                       // A: selection (t-1) + compute reads done
        for (int i = tid; i < CC * 64; i += 256) {
            int c = i >> 6, jj = i & 63;
            candT[c][jj] = (double)xb[(size_t)c * NNN + j0 + jj];
        }
        __syncthreads();                       // B: candT ready
        double a0 = 0.0, a1 = 0.0, a2 = 0.0, a3 = 0.0;
        for (int c = 0; c < CC; ++c) {
            double rv = rowT[c][r];                            // 4-lane broadcast
            double2 cA = *(const double2*)&candT[c][jg * 4];   // 16-lane broadcast
            double2 cB = *(const double2*)&candT[c][jg * 4 + 2];
            a0 = fma(rv, cA.x, a0);
            a1 = fma(rv, cA.y, a1);
            a2 = fma(rv, cB.x, a2);
            a3 = fma(rv, cB.y, a3);
        }
        {
            double xr2 = xxr[r];
            const double* xq = xx + (size_t)b * NNN + j0 + jg * 4;
            distK[r][jg * 4 + 0] = packkey(2.0 * a0 - xr2 - xq[0], j0 + jg * 4 + 0);
            distK[r][jg * 4 + 1] = packkey(2.0 * a1 - xr2 - xq[1], j0 + jg * 4 + 1);
            distK[r][jg * 4 + 2] = packkey(2.0 * a2 - xr2 - xq[2], j0 + jg * 4 + 2);
            distK[r][jg * 4 + 3] = packkey(2.0 * a3 - xr2 - xq[3], j0 + jg * 4 + 3);
        }
        __syncthreads();                       // C: distK ready
        // wave-parallel selection: wave w handles rows 4w+0..3; all lanes converged
        #define SELROW(RL) { \
            unsigned long long key = distK[w * 4 + RL][lane]; \
            unsigned long long m = __ballot(key > T##RL); \
            while (m) { \
                int src = (int)__builtin_ctzll(m); m &= m - 1; \
                unsigned long long kb = __shfl(key, src); \
                if (kb > T##RL) { \
                    unsigned long long u = __shfl_down(S##RL, 1); \
                    unsigned long long mx = (S##RL < kb) ? kb : S##RL; \
                    S##RL = (u < kb) ? u : mx; \
                    T##RL = __shfl(S##RL, 0); \
                } \
            } \
        }
        SELROW(0) SELROW(1) SELROW(2) SELROW(3)
        #undef SELROW
    }

    // extraction: sorted ascending across lanes 0..19 -> out[q] descending
    if (lane < KK) {
        size_t base = ((size_t)b * NNN + r0 + w * 4) * KK;
        idxOut[base + 0 * KK + (KK - 1 - lane)] = 4095 - (int)(S0 & 0xFFFULL);
        idxOut[base + 1 * KK + (KK - 1 - lane)] = 4095 - (int)(S1 & 0xFFFULL);
        idxOut[base + 2 * KK + (KK - 1 - lane)] = 4095 - (int)(S2 & 0xFFFULL);
        idxOut[base + 3 * KK + (KK - 1 - lane)] = 4095 - (int)(S3 & 0xFFFULL);
    }
}

// ---------------- K4: h1 = relu(bn1(A[nb]+Bv[n])); h2 = relu(bn2(h1·w2^T)); max over k ----------------
__global__ __launch_bounds__(256) void edge_kernel(const float* __restrict__ A, const float* __restrict__ Bv,
        const int* __restrict__ idx, const float* __restrict__ w2,
        const float* __restrict__ g1, const float* __restrict__ be1, const float* __restrict__ m1, const float* __restrict__ v1,
        const float* __restrict__ g2, const float* __restrict__ be2, const float* __restrict__ m2, const float* __restrict__ v2,
        float* __restrict__ out) {
    __shared__ float h1buf[4][KK][64];
    __shared__ float resT[64][33];
    int tid = threadIdx.x;
    int lane = tid & 63, w = tid >> 6;
    int b = blockIdx.x >> 7;
    int n0 = (blockIdx.x & 127) * 32;
    float s1 = g1[lane] * rsqrtf(v1[lane] + EPSF);
    float bb1 = be1[lane] - m1[lane] * s1;
    float s2 = g2[lane] * rsqrtf(v2[lane] + EPSF);
    float bb2 = be2[lane] - m2[lane] * s2;
    float w2r[64];
    #pragma unroll
    for (int o = 0; o < 64; ++o) w2r[o] = w2[lane * 64 + o];
    for (int p = 0; p < 8; ++p) {
        int n = n0 + w * 8 + p;
        size_t pb = (size_t)b * NNN + n;
        float bv = Bv[pb * 64 + lane];
        const int* ip = idx + pb * KK;
        #pragma unroll
        for (int k = 0; k < KK; ++k) {
            int nb = ip[k];
            float av = A[((size_t)b * NNN + nb) * 64 + lane];
            h1buf[w][k][lane] = fmaxf(0.f, fmaf(av + bv, s1, bb1));
        }
        __syncthreads();
        float mx = -1e30f;
        for (int k = 0; k < KK; ++k) {
            const float4* hb = (const float4*)&h1buf[w][k][0];
            float dot = 0.f;
            #pragma unroll
            for (int o4 = 0; o4 < 16; ++o4) {
                float4 h = hb[o4];
                dot = fmaf(w2r[o4 * 4 + 0], h.x, dot);
                dot = fmaf(w2r[o4 * 4 + 1], h.y, dot);
                dot = fmaf(w2r[o4 * 4 + 2], h.z, dot);
                dot = fmaf(w2r[o4 * 4 + 3], h.w, dot);
            }
            mx = fmaxf(mx, fmaxf(0.f, fmaf(dot, s2, bb2)));
        }
        resT[lane][w * 8 + p] = mx;
        __syncthreads();
    }
    for (int i = tid; i < 64 * 32; i += 256) {
        int o2 = i >> 5, pp = i & 31;
        out[((size_t)b * 64 + o2) * NNN + n0 + pp] = resT[o2][pp];
    }
}

extern "C" void kernel_launch(void* const* d_in, const int* in_sizes, int n_in,
                              void* d_out, int out_size, void* d_ws, size_t ws_size,
                              hipStream_t stream) {
    const float* x   = (const float*)d_in[0];
    const float* w1  = (const float*)d_in[1];
    const float* g1  = (const float*)d_in[2];
    const float* be1 = (const float*)d_in[3];
    const float* m1  = (const float*)d_in[4];
    const float* v1  = (const float*)d_in[5];
    const float* w2  = (const float*)d_in[6];
    const float* g2  = (const float*)d_in[7];
    const float* be2 = (const float*)d_in[8];
    const float* m2  = (const float*)d_in[9];
    const float* v2  = (const float*)d_in[10];
    // ws layout: xx f64 (128KB) | A f32 (4MB) | Bv f32 (4MB) | idx i32 (1.25MB)
    char* ws = (char*)d_ws;
    double* xx = (double*)ws;
    float*  A  = (float*)(ws + 131072);
    float*  Bv = (float*)(ws + 131072 + 4194304);
    int*    nidx = (int*)(ws + 131072 + 2 * 4194304);
    float*  out = (float*)d_out;

    hipLaunchKernelGGL(xx_kernel,   dim3(BB * NNN / 256), dim3(256), 0, stream, x, xx);
    hipLaunchKernelGGL(proj_kernel, dim3(BB * (NNN / 64)), dim3(256), 0, stream, x, w1, A, Bv);
    hipLaunchKernelGGL(knn_kernel,  dim3(BB * (NNN / 16)), dim3(256), 0, stream, x, xx, nidx);
    hipLaunchKernelGGL(edge_kernel, dim3(BB * (NNN / 32)), dim3(256), 0, stream,
                       A, Bv, nidx, w2, g1, be1, m1, v1, g2, be2, m2, v2, out);
}

// Round 9
// 674.049 us; speedup vs baseline: 29.8028x; 1.5918x over previous
//
#include <hip/hip_runtime.h>

#define BB 4
#define CC 64
#define NNN 4096
#define OO 64
#define KK 20
#define EPSF 1e-5f

typedef __attribute__((ext_vector_type(4))) double d4;

// ---------------- K1: xx[n] = sum_c x[c][n]^2 in f64 ----------------
__global__ __launch_bounds__(256) void xx_kernel(const float* __restrict__ x, double* __restrict__ xx) {
    int g = blockIdx.x * 256 + threadIdx.x;          // 0..B*N-1
    int b = g >> 12, n = g & (NNN - 1);
    const float* xp = x + (size_t)b * CC * NNN + n;
    double s = 0.0;
    for (int c = 0; c < CC; ++c) {
        double v = (double)xp[(size_t)c * NNN];
        s += v * v;
    }
    xx[g] = s;
}

// ---------------- K2: per-point projections A = x*w1a^T, Bv = x*(w1b-w1a)^T ----------------
__global__ __launch_bounds__(256) void proj_kernel(const float* __restrict__ x, const float* __restrict__ w1,
                                                   float* __restrict__ A, float* __restrict__ Bv) {
    __shared__ float xs[CC][64];       // [c][p]
    __shared__ float ws1[OO][129];     // padded
    int tid = threadIdx.x;
    int b = blockIdx.x >> 6;
    int p0 = (blockIdx.x & 63) << 6;
    const float* xb = x + (size_t)b * CC * NNN;
    for (int i = tid; i < CC * 16; i += 256) {
        int c = i >> 4, q = i & 15;
        *(float4*)&xs[c][q * 4] = *(const float4*)(xb + (size_t)c * NNN + p0 + q * 4);
    }
    for (int i = tid; i < OO * 32; i += 256) {
        int o = i >> 5, q = i & 31;
        float4 v = *(const float4*)(w1 + o * 128 + q * 4);
        ws1[o][q * 4 + 0] = v.x; ws1[o][q * 4 + 1] = v.y;
        ws1[o][q * 4 + 2] = v.z; ws1[o][q * 4 + 3] = v.w;
    }
    __syncthreads();
    int ti = tid >> 4, tj = tid & 15;
    float aA[4][4] = {{0.f}}, aD[4][4] = {{0.f}};
    for (int c = 0; c < CC; ++c) {
        float4 xv4 = *(const float4*)&xs[c][ti * 4];
        float xv[4] = {xv4.x, xv4.y, xv4.z, xv4.w};
        #pragma unroll
        for (int oo = 0; oo < 4; ++oo) {
            float wa = ws1[tj * 4 + oo][c];
            float wd = ws1[tj * 4 + oo][64 + c] - wa;
            #pragma unroll
            for (int pp = 0; pp < 4; ++pp) {
                aA[pp][oo] = fmaf(xv[pp], wa, aA[pp][oo]);
                aD[pp][oo] = fmaf(xv[pp], wd, aD[pp][oo]);
            }
        }
    }
    size_t base = ((size_t)b * NNN + p0) * 64;
    #pragma unroll
    for (int pp = 0; pp < 4; ++pp) {
        int p = ti * 4 + pp;
        *(float4*)(A  + base + (size_t)p * 64 + tj * 4) = make_float4(aA[pp][0], aA[pp][1], aA[pp][2], aA[pp][3]);
        *(float4*)(Bv + base + (size_t)p * 64 + tj * 4) = make_float4(aD[pp][0], aD[pp][1], aD[pp][2], aD[pp][3]);
    }
}

// ---------------- K3: f64 MFMA distances (runtime layout probe) + sorted-lane top-20 ----------------
// 512 blocks (2/CU). Block = 32 rows x 4096 cands, 64-cand rounds.
// Wave (rg=w>>1, cg=w&1): rows rg*16..+15 x cands cg*32..+31 via v_mfma_f64_16x16x4.
// D-layout is MEASURED at runtime: probe pA=mfma(lane&15, 1) -> pA[r]=4*rowlabel,
// pB=mfma(1, lane&15) -> pB[r]=4*collabel. Epilogue indexes by measured labels ->
// correct under ANY bijective D mapping. Selection: r7-validated lane-sorted lists.

__device__ __forceinline__ unsigned long long packkey(double d, int j) {
    unsigned long long u = __double_as_longlong(d);
    u ^= (unsigned long long)((long long)u >> 63) | 0x8000000000000000ULL;
    return (u & ~0xFFFULL) | (unsigned long long)(4095 - j);
}

__global__ __launch_bounds__(256) void knn_kernel(const float* __restrict__ x, const double* __restrict__ xx,
                                                  int* __restrict__ idxOut) {
    __shared__ double rowT[CC][33];              // 16896 B
    __shared__ double candT[CC][65];             // 33280 B
    __shared__ unsigned long long distK[32][65]; // 16640 B
    __shared__ double xxcL[64];                  //   512 B -> 67328 B = 2 blocks/CU
    int tid = threadIdx.x;
    int lane = tid & 63, w = tid >> 6;
    int b  = blockIdx.x >> 7;                    // 128 blocks per batch
    int r0 = (blockIdx.x & 127) * 32;
    const float* xb = x + (size_t)b * CC * NNN;
    const double* xxb = xx + (size_t)b * NNN;

    // ---- layout probe (2 MFMAs, once) ----
    double pv = (double)(lane & 15);
    d4 z4 = {0.0, 0.0, 0.0, 0.0};
    d4 pA = __builtin_amdgcn_mfma_f64_16x16x4f64(pv, 1.0, z4, 0, 0, 0);
    d4 pB = __builtin_amdgcn_mfma_f64_16x16x4f64(1.0, pv, z4, 0, 0, 0);
    int mA0 = (int)(pA[0] * 0.25), mA1 = (int)(pA[1] * 0.25),
        mA2 = (int)(pA[2] * 0.25), mA3 = (int)(pA[3] * 0.25);
    int mB0 = (int)(pB[0] * 0.25), mB1 = (int)(pB[1] * 0.25),
        mB2 = (int)(pB[2] * 0.25), mB3 = (int)(pB[3] * 0.25);

    for (int i = tid; i < CC * 32; i += 256) {   // stage rowT once
        int c = i >> 5, rr = i & 31;
        rowT[c][rr] = (double)xb[(size_t)c * NNN + r0 + rr];
    }
    int rg = w >> 1, cg = w & 1;
    int lr = lane & 15, lk = lane >> 4;
    // per-reg measured output coordinates
    int rA0 = rg * 16 + mA0, rA1 = rg * 16 + mA1, rA2 = rg * 16 + mA2, rA3 = rg * 16 + mA3;
    int cA0 = cg * 32 + mB0, cA1 = cg * 32 + mB1, cA2 = cg * 32 + mB2, cA3 = cg * 32 + mB3;
    double xr0 = xxb[r0 + rA0], xr1 = xxb[r0 + rA1], xr2 = xxb[r0 + rA2], xr3 = xxb[r0 + rA3];

    // per-wave sorted lists for rows w*8..w*8+7 (ascending across lanes 0..19)
    unsigned long long S0, S1, S2, S3, S4, S5, S6, S7;
    S0 = S1 = S2 = S3 = S4 = S5 = S6 = S7 = (lane < KK) ? 0ULL : ~0ULL;
    unsigned long long T0 = 0, T1 = 0, T2 = 0, T3 = 0, T4 = 0, T5 = 0, T6 = 0, T7 = 0;

    #define SELROW(RL) { \
        unsigned long long key = distK[w * 8 + RL][lane]; \
        unsigned long long m = __ballot(key > T##RL); \
        while (m) { \
            int src = (int)__builtin_ctzll(m); m &= m - 1; \
            unsigned long long kb = __shfl(key, src); \
            if (kb > T##RL) { \
                unsigned long long u = __shfl_down(S##RL, 1); \
                unsigned long long mx = (S##RL < kb) ? kb : S##RL; \
                S##RL = (u < kb) ? u : mx; \
                T##RL = __shfl(S##RL, 0); \
            } \
        } \
    }
    #define SELALL() SELROW(0) SELROW(1) SELROW(2) SELROW(3) SELROW(4) SELROW(5) SELROW(6) SELROW(7)

    for (int t = 0; t < 64; ++t) {
        int j0 = t * 64;
        __syncthreads();                   // C: distK(t-1) complete, candT(t-1) reads done
        if (t > 0) { SELALL(); }           // select(t-1): reads distK only
        for (int i = tid; i < CC * 64; i += 256) {   // stage candT(t)
            int c = i >> 6, jj = i & 63;
            candT[c][jj] = (double)xb[(size_t)c * NNN + j0 + jj];
        }
        if (tid < 64) xxcL[tid] = xxb[j0 + tid];
        __syncthreads();                   // B: candT/xxcL ready, select(t-1) done
        d4 acc0 = {0.0, 0.0, 0.0, 0.0}, acc1 = {0.0, 0.0, 0.0, 0.0};
        #pragma unroll
        for (int k = 0; k < 16; ++k) {
            double av = rowT[k * 4 + lk][rg * 16 + lr];
            double b0 = candT[k * 4 + lk][cg * 32 + lr];
            double b1 = candT[k * 4 + lk][cg * 32 + 16 + lr];
            acc0 = __builtin_amdgcn_mfma_f64_16x16x4f64(av, b0, acc0, 0, 0, 0);
            acc1 = __builtin_amdgcn_mfma_f64_16x16x4f64(av, b1, acc1, 0, 0, 0);
        }
        // epilogue: measured (row, col) labels per accumulator slot
        #define EPI(R) { \
            int ca = cA##R, cb = cA##R + 16; \
            double xqa = xxcL[ca], xqb = xxcL[cb]; \
            distK[rA##R][ca] = packkey(2.0 * acc0[R] - xr##R - xqa, j0 + ca); \
            distK[rA##R][cb] = packkey(2.0 * acc1[R] - xr##R - xqb, j0 + cb); \
        }
        EPI(0) EPI(1) EPI(2) EPI(3)
        #undef EPI
    }
    __syncthreads();                       // final distK ready
    SELALL();
    #undef SELALL
    #undef SELROW

    if (lane < KK) {                       // lists ascending -> out descending
        size_t base = ((size_t)b * NNN + r0 + w * 8) * KK;
        idxOut[base + 0 * KK + (KK - 1 - lane)] = 4095 - (int)(S0 & 0xFFFULL);
        idxOut[base + 1 * KK + (KK - 1 - lane)] = 4095 - (int)(S1 & 0xFFFULL);
        idxOut[base + 2 * KK + (KK - 1 - lane)] = 4095 - (int)(S2 & 0xFFFULL);
        idxOut[base + 3 * KK + (KK - 1 - lane)] = 4095 - (int)(S3 & 0xFFFULL);
        idxOut[base + 4 * KK + (KK - 1 - lane)] = 4095 - (int)(S4 & 0xFFFULL);
        idxOut[base + 5 * KK + (KK - 1 - lane)] = 4095 - (int)(S5 & 0xFFFULL);
        idxOut[base + 6 * KK + (KK - 1 - lane)] = 4095 - (int)(S6 & 0xFFFULL);
        idxOut[base + 7 * KK + (KK - 1 - lane)] = 4095 - (int)(S7 & 0xFFFULL);
    }
}

// ---------------- K4: h1 = relu(bn1(A[nb]+Bv[n])); h2 = relu(bn2(h1·w2^T)); max over k ----------------
__global__ __launch_bounds__(256) void edge_kernel(const float* __restrict__ A, const float* __restrict__ Bv,
        const int* __restrict__ idx, const float* __restrict__ w2,
        const float* __restrict__ g1, const float* __restrict__ be1, const float* __restrict__ m1, const float* __restrict__ v1,
        const float* __restrict__ g2, const float* __restrict__ be2, const float* __restrict__ m2, const float* __restrict__ v2,
        float* __restrict__ out) {
    __shared__ float h1buf[4][KK][64];
    __shared__ float resT[64][33];
    int tid = threadIdx.x;
    int lane = tid & 63, w = tid >> 6;
    int b = blockIdx.x >> 7;
    int n0 = (blockIdx.x & 127) * 32;
    float s1 = g1[lane] * rsqrtf(v1[lane] + EPSF);
    float bb1 = be1[lane] - m1[lane] * s1;
    float s2 = g2[lane] * rsqrtf(v2[lane] + EPSF);
    float bb2 = be2[lane] - m2[lane] * s2;
    float w2r[64];
    #pragma unroll
    for (int o = 0; o < 64; ++o) w2r[o] = w2[lane * 64 + o];
    for (int p = 0; p < 8; ++p) {
        int n = n0 + w * 8 + p;
        size_t pb = (size_t)b * NNN + n;
        float bv = Bv[pb * 64 + lane];
        const int* ip = idx + pb * KK;
        #pragma unroll
        for (int k = 0; k < KK; ++k) {
            int nb = ip[k];
            float av = A[((size_t)b * NNN + nb) * 64 + lane];
            h1buf[w][k][lane] = fmaxf(0.f, fmaf(av + bv, s1, bb1));
        }
        __syncthreads();
        float mx = -1e30f;
        for (int k = 0; k < KK; ++k) {
            const float4* hb = (const float4*)&h1buf[w][k][0];
            float dot = 0.f;
            #pragma unroll
            for (int o4 = 0; o4 < 16; ++o4) {
                float4 h = hb[o4];
                dot = fmaf(w2r[o4 * 4 + 0], h.x, dot);
                dot = fmaf(w2r[o4 * 4 + 1], h.y, dot);
                dot = fmaf(w2r[o4 * 4 + 2], h.z, dot);
                dot = fmaf(w2r[o4 * 4 + 3], h.w, dot);
            }
            mx = fmaxf(mx, fmaxf(0.f, fmaf(dot, s2, bb2)));
        }
        resT[lane][w * 8 + p] = mx;
        __syncthreads();
    }
    for (int i = tid; i < 64 * 32; i += 256) {
        int o2 = i >> 5, pp = i & 31;
        out[((size_t)b * 64 + o2) * NNN + n0 + pp] = resT[o2][pp];
    }
}

extern "C" void kernel_launch(void* const* d_in, const int* in_sizes, int n_in,
                              void* d_out, int out_size, void* d_ws, size_t ws_size,
                              hipStream_t stream) {
    const float* x   = (const float*)d_in[0];
    const float* w1  = (const float*)d_in[1];
    const float* g1  = (const float*)d_in[2];
    const float* be1 = (const float*)d_in[3];
    const float* m1  = (const float*)d_in[4];
    const float* v1  = (const float*)d_in[5];
    const float* w2  = (const float*)d_in[6];
    const float* g2  = (const float*)d_in[7];
    const float* be2 = (const float*)d_in[8];
    const float* m2  = (const float*)d_in[9];
    const float* v2  = (const float*)d_in[10];
    // ws layout: xx f64 (128KB) | A f32 (4MB) | Bv f32 (4MB) | idx i32 (1.25MB)
    char* ws = (char*)d_ws;
    double* xx = (double*)ws;
    float*  A  = (float*)(ws + 131072);
    float*  Bv = (float*)(ws + 131072 + 4194304);
    int*    nidx = (int*)(ws + 131072 + 2 * 4194304);
    float*  out = (float*)d_out;

    hipLaunchKernelGGL(xx_kernel,   dim3(BB * NNN / 256), dim3(256), 0, stream, x, xx);
    hipLaunchKernelGGL(proj_kernel, dim3(BB * (NNN / 64)), dim3(256), 0, stream, x, w1, A, Bv);
    hipLaunchKernelGGL(knn_kernel,  dim3(BB * (NNN / 32)), dim3(256), 0, stream, x, xx, nidx);
    hipLaunchKernelGGL(edge_kernel, dim3(BB * (NNN / 32)), dim3(256), 0, stream,
                       A, Bv, nidx, w2, g1, be1, m1, v1, g2, be2, m2, v2, out);
}

// Round 11
// 494.289 us; speedup vs baseline: 40.6413x; 1.3637x over previous
//
#include <hip/hip_runtime.h>

#define BB 4
#define CC 64
#define NNN 4096
#define OO 64
#define KK 20
#define EPSF 1e-5f

typedef __attribute__((ext_vector_type(4))) double d4;

// ---------------- K1: xx[n] = sum_c x[c][n]^2 in f64 ----------------
__global__ __launch_bounds__(256) void xx_kernel(const float* __restrict__ x, double* __restrict__ xx) {
    int g = blockIdx.x * 256 + threadIdx.x;          // 0..B*N-1
    int b = g >> 12, n = g & (NNN - 1);
    const float* xp = x + (size_t)b * CC * NNN + n;
    double s = 0.0;
    for (int c = 0; c < CC; ++c) {
        double v = (double)xp[(size_t)c * NNN];
        s += v * v;
    }
    xx[g] = s;
}

// ---------------- K2: per-point projections A = x*w1a^T, Bv = x*(w1b-w1a)^T ----------------
__global__ __launch_bounds__(256) void proj_kernel(const float* __restrict__ x, const float* __restrict__ w1,
                                                   float* __restrict__ A, float* __restrict__ Bv) {
    __shared__ float xs[CC][64];       // [c][p]
    __shared__ float ws1[OO][129];     // padded
    int tid = threadIdx.x;
    int b = blockIdx.x >> 6;
    int p0 = (blockIdx.x & 63) << 6;
    const float* xb = x + (size_t)b * CC * NNN;
    for (int i = tid; i < CC * 16; i += 256) {
        int c = i >> 4, q = i & 15;
        *(float4*)&xs[c][q * 4] = *(const float4*)(xb + (size_t)c * NNN + p0 + q * 4);
    }
    for (int i = tid; i < OO * 32; i += 256) {
        int o = i >> 5, q = i & 31;
        float4 v = *(const float4*)(w1 + o * 128 + q * 4);
        ws1[o][q * 4 + 0] = v.x; ws1[o][q * 4 + 1] = v.y;
        ws1[o][q * 4 + 2] = v.z; ws1[o][q * 4 + 3] = v.w;
    }
    __syncthreads();
    int ti = tid >> 4, tj = tid & 15;
    float aA[4][4] = {{0.f}}, aD[4][4] = {{0.f}};
    for (int c = 0; c < CC; ++c) {
        float4 xv4 = *(const float4*)&xs[c][ti * 4];
        float xv[4] = {xv4.x, xv4.y, xv4.z, xv4.w};
        #pragma unroll
        for (int oo = 0; oo < 4; ++oo) {
            float wa = ws1[tj * 4 + oo][c];
            float wd = ws1[tj * 4 + oo][64 + c] - wa;
            #pragma unroll
            for (int pp = 0; pp < 4; ++pp) {
                aA[pp][oo] = fmaf(xv[pp], wa, aA[pp][oo]);
                aD[pp][oo] = fmaf(xv[pp], wd, aD[pp][oo]);
            }
        }
    }
    size_t base = ((size_t)b * NNN + p0) * 64;
    #pragma unroll
    for (int pp = 0; pp < 4; ++pp) {
        int p = ti * 4 + pp;
        *(float4*)(A  + base + (size_t)p * 64 + tj * 4) = make_float4(aA[pp][0], aA[pp][1], aA[pp][2], aA[pp][3]);
        *(float4*)(Bv + base + (size_t)p * 64 + tj * 4) = make_float4(aD[pp][0], aD[pp][1], aD[pp][2], aD[pp][3]);
    }
}

// ---------------- K3: f64 MFMA distances (probe layout) + sorted-lane top-20 ----------------
// 512 blocks (2/CU, LDS 81408B). Block = 32 rows x 4096 cands, 128-cand tiles.
// 4 waves: wave (rg=w>>1, cg=w&1) computes rows rg*16..+15 x cols cg*64..+63 via
// 4 independent MFMA chains. Selection: wave w owns rows w*8..w*8+7 (4x8=32: all
// rows covered -- r10's 4-rows/wave left rows 16..31 unwritten -> poisoned idx -> OOB).

__device__ __forceinline__ unsigned long long packkey(double d, int j) {
    unsigned long long u = __double_as_longlong(d);
    u ^= (unsigned long long)((long long)u >> 63) | 0x8000000000000000ULL;
    return (u & ~0xFFFULL) | (unsigned long long)(4095 - j);
}

__global__ __launch_bounds__(256) void knn_kernel(const float* __restrict__ x, const double* __restrict__ xx,
                                                  int* __restrict__ idxOut) {
    __shared__ float rowT[CC][48];               // 12288 B (stride 48: 2-way, free)
    __shared__ float candT[CC][136];             // 34816 B (stride 136: 2-way, free)
    __shared__ unsigned long long distK[32][130];// 33280 B
    __shared__ double xxcL[128];                 //  1024 B -> 81408 B total = 2 blocks/CU
    int tid = threadIdx.x;
    int lane = tid & 63, w = tid >> 6;           // 4 waves
    int b  = blockIdx.x >> 7;                    // 128 blocks per batch
    int r0 = (blockIdx.x & 127) * 32;
    const float* xb = x + (size_t)b * CC * NNN;
    const double* xxb = xx + (size_t)b * NNN;

    // ---- layout probe (2 MFMAs, once) ----
    double pv = (double)(lane & 15);
    d4 z4 = {0.0, 0.0, 0.0, 0.0};
    d4 pA = __builtin_amdgcn_mfma_f64_16x16x4f64(pv, 1.0, z4, 0, 0, 0);
    d4 pB = __builtin_amdgcn_mfma_f64_16x16x4f64(1.0, pv, z4, 0, 0, 0);
    int mA0 = (int)(pA[0] * 0.25), mA1 = (int)(pA[1] * 0.25),
        mA2 = (int)(pA[2] * 0.25), mA3 = (int)(pA[3] * 0.25);
    int mB0 = (int)(pB[0] * 0.25), mB1 = (int)(pB[1] * 0.25),
        mB2 = (int)(pB[2] * 0.25), mB3 = (int)(pB[3] * 0.25);

    for (int i = tid; i < CC * 32; i += 256) {   // stage rowT once (f32)
        int c = i >> 5, rr = i & 31;
        rowT[c][rr] = xb[(size_t)c * NNN + r0 + rr];
    }
    int rg = w >> 1, cg = w & 1;
    int lr = lane & 15, lk = lane >> 4;
    int rA0 = rg * 16 + mA0, rA1 = rg * 16 + mA1, rA2 = rg * 16 + mA2, rA3 = rg * 16 + mA3;
    double xr0 = xxb[r0 + rA0], xr1 = xxb[r0 + rA1], xr2 = xxb[r0 + rA2], xr3 = xxb[r0 + rA3];

    // per-wave sorted lists for rows w*8..w*8+7 (ascending across lanes 0..19)
    unsigned long long S0, S1, S2, S3, S4, S5, S6, S7;
    S0 = S1 = S2 = S3 = S4 = S5 = S6 = S7 = (lane < KK) ? 0ULL : ~0ULL;
    unsigned long long T0 = 0, T1 = 0, T2 = 0, T3 = 0, T4 = 0, T5 = 0, T6 = 0, T7 = 0;

    #define SELROW(RL) { \
        for (int hf = 0; hf < 2; ++hf) { \
            unsigned long long key = distK[w * 8 + RL][hf * 64 + lane]; \
            unsigned long long m = __ballot(key > T##RL); \
            while (m) { \
                int src = (int)__builtin_ctzll(m); m &= m - 1; \
                unsigned long long kb = __shfl(key, src); \
                if (kb > T##RL) { \
                    unsigned long long u = __shfl_down(S##RL, 1); \
                    unsigned long long mx = (S##RL < kb) ? kb : S##RL; \
                    S##RL = (u < kb) ? u : mx; \
                    T##RL = __shfl(S##RL, 0); \
                } \
            } \
        } \
    }
    #define SELALL() SELROW(0) SELROW(1) SELROW(2) SELROW(3) SELROW(4) SELROW(5) SELROW(6) SELROW(7)

    for (int t = 0; t < 32; ++t) {
        int j0 = t * 128;
        __syncthreads();                   // A: distK(t-1) complete, candT(t-1) reads done
        if (t > 0) { SELALL(); }           // select(t-1): reads distK only
        for (int cc = w; cc < CC; cc += 4) {         // stage candT(t), f32
            candT[cc][lane]      = xb[(size_t)cc * NNN + j0 + lane];
            candT[cc][64 + lane] = xb[(size_t)cc * NNN + j0 + 64 + lane];
        }
        if (tid < 128) xxcL[tid] = xxb[j0 + tid];
        __syncthreads();                   // B: candT/xxcL ready, select(t-1) done
        d4 acc0 = {0.0, 0.0, 0.0, 0.0}, acc1 = {0.0, 0.0, 0.0, 0.0};
        d4 acc2 = {0.0, 0.0, 0.0, 0.0}, acc3 = {0.0, 0.0, 0.0, 0.0};
        #pragma unroll
        for (int k = 0; k < 16; ++k) {
            double av = (double)rowT[k * 4 + lk][rg * 16 + lr];
            double b0 = (double)candT[k * 4 + lk][cg * 64 + lr];
            double b1 = (double)candT[k * 4 + lk][cg * 64 + 16 + lr];
            double b2 = (double)candT[k * 4 + lk][cg * 64 + 32 + lr];
            double b3 = (double)candT[k * 4 + lk][cg * 64 + 48 + lr];
            acc0 = __builtin_amdgcn_mfma_f64_16x16x4f64(av, b0, acc0, 0, 0, 0);
            acc1 = __builtin_amdgcn_mfma_f64_16x16x4f64(av, b1, acc1, 0, 0, 0);
            acc2 = __builtin_amdgcn_mfma_f64_16x16x4f64(av, b2, acc2, 0, 0, 0);
            acc3 = __builtin_amdgcn_mfma_f64_16x16x4f64(av, b3, acc3, 0, 0, 0);
        }
        // epilogue: measured labels; chain Q covers cols cg*64 + Q*16 + mB_i
        #define EPI(Q, R) { \
            int col = cg * 64 + Q * 16 + mB##R; \
            distK[rA##R][col] = packkey(2.0 * acc##Q[R] - xr##R - xxcL[col], j0 + col); \
        }
        EPI(0,0) EPI(0,1) EPI(0,2) EPI(0,3)
        EPI(1,0) EPI(1,1) EPI(1,2) EPI(1,3)
        EPI(2,0) EPI(2,1) EPI(2,2) EPI(2,3)
        EPI(3,0) EPI(3,1) EPI(3,2) EPI(3,3)
        #undef EPI
    }
    __syncthreads();                       // final distK ready
    SELALL();
    #undef SELALL
    #undef SELROW

    if (lane < KK) {                       // lists ascending -> out descending
        size_t base = ((size_t)b * NNN + r0 + w * 8) * KK;
        idxOut[base + 0 * KK + (KK - 1 - lane)] = 4095 - (int)(S0 & 0xFFFULL);
        idxOut[base + 1 * KK + (KK - 1 - lane)] = 4095 - (int)(S1 & 0xFFFULL);
        idxOut[base + 2 * KK + (KK - 1 - lane)] = 4095 - (int)(S2 & 0xFFFULL);
        idxOut[base + 3 * KK + (KK - 1 - lane)] = 4095 - (int)(S3 & 0xFFFULL);
        idxOut[base + 4 * KK + (KK - 1 - lane)] = 4095 - (int)(S4 & 0xFFFULL);
        idxOut[base + 5 * KK + (KK - 1 - lane)] = 4095 - (int)(S5 & 0xFFFULL);
        idxOut[base + 6 * KK + (KK - 1 - lane)] = 4095 - (int)(S6 & 0xFFFULL);
        idxOut[base + 7 * KK + (KK - 1 - lane)] = 4095 - (int)(S7 & 0xFFFULL);
    }
}

// ---------------- K4: h1 = relu(bn1(A[nb]+Bv[n])); h2 = relu(bn2(h1·w2^T)); max over k ----------------
__global__ __launch_bounds__(256) void edge_kernel(const float* __restrict__ A, const float* __restrict__ Bv,
        const int* __restrict__ idx, const float* __restrict__ w2,
        const float* __restrict__ g1, const float* __restrict__ be1, const float* __restrict__ m1, const float* __restrict__ v1,
        const float* __restrict__ g2, const float* __restrict__ be2, const float* __restrict__ m2, const float* __restrict__ v2,
        float* __restrict__ out) {
    __shared__ float h1buf[4][KK][64];
    __shared__ float resT[64][33];
    int tid = threadIdx.x;
    int lane = tid & 63, w = tid >> 6;
    int b = blockIdx.x >> 7;
    int n0 = (blockIdx.x & 127) * 32;
    float s1 = g1[lane] * rsqrtf(v1[lane] + EPSF);
    float bb1 = be1[lane] - m1[lane] * s1;
    float s2 = g2[lane] * rsqrtf(v2[lane] + EPSF);
    float bb2 = be2[lane] - m2[lane] * s2;
    float w2r[64];
    #pragma unroll
    for (int o = 0; o < 64; ++o) w2r[o] = w2[lane * 64 + o];
    for (int p = 0; p < 8; ++p) {
        int n = n0 + w * 8 + p;
        size_t pb = (size_t)b * NNN + n;
        float bv = Bv[pb * 64 + lane];
        const int* ip = idx + pb * KK;
        #pragma unroll
        for (int k = 0; k < KK; ++k) {
            int nb = ip[k];
            float av = A[((size_t)b * NNN + nb) * 64 + lane];
            h1buf[w][k][lane] = fmaxf(0.f, fmaf(av + bv, s1, bb1));
        }
        __syncthreads();
        float mx = -1e30f;
        for (int k = 0; k < KK; ++k) {
            const float4* hb = (const float4*)&h1buf[w][k][0];
            float dot = 0.f;
            #pragma unroll
            for (int o4 = 0; o4 < 16; ++o4) {
                float4 h = hb[o4];
                dot = fmaf(w2r[o4 * 4 + 0], h.x, dot);
                dot = fmaf(w2r[o4 * 4 + 1], h.y, dot);
                dot = fmaf(w2r[o4 * 4 + 2], h.z, dot);
                dot = fmaf(w2r[o4 * 4 + 3], h.w, dot);
            }
            mx = fmaxf(mx, fmaxf(0.f, fmaf(dot, s2, bb2)));
        }
        resT[lane][w * 8 + p] = mx;
        __syncthreads();
    }
    for (int i = tid; i < 64 * 32; i += 256) {
        int o2 = i >> 5, pp = i & 31;
        out[((size_t)b * 64 + o2) * NNN + n0 + pp] = resT[o2][pp];
    }
}

extern "C" void kernel_launch(void* const* d_in, const int* in_sizes, int n_in,
                              void* d_out, int out_size, void* d_ws, size_t ws_size,
                              hipStream_t stream) {
    const float* x   = (const float*)d_in[0];
    const float* w1  = (const float*)d_in[1];
    const float* g1  = (const float*)d_in[2];
    const float* be1 = (const float*)d_in[3];
    const float* m1  = (const float*)d_in[4];
    const float* v1  = (const float*)d_in[5];
    const float* w2  = (const float*)d_in[6];
    const float* g2  = (const float*)d_in[7];
    const float* be2 = (const float*)d_in[8];
    const float* m2  = (const float*)d_in[9];
    const float* v2  = (const float*)d_in[10];
    // ws layout: xx f64 (128KB) | A f32 (4MB) | Bv f32 (4MB) | idx i32 (1.25MB)
    char* ws = (char*)d_ws;
    double* xx = (double*)ws;
    float*  A  = (float*)(ws + 131072);
    float*  Bv = (float*)(ws + 131072 + 4194304);
    int*    nidx = (int*)(ws + 131072 + 2 * 4194304);
    float*  out = (float*)d_out;

    hipLaunchKernelGGL(xx_kernel,   dim3(BB * NNN / 256), dim3(256), 0, stream, x, xx);
    hipLaunchKernelGGL(proj_kernel, dim3(BB * (NNN / 64)), dim3(256), 0, stream, x, w1, A, Bv);
    hipLaunchKernelGGL(knn_kernel,  dim3(BB * (NNN / 32)), dim3(256), 0, stream, x, xx, nidx);
    hipLaunchKernelGGL(edge_kernel, dim3(BB * (NNN / 32)), dim3(256), 0, stream,
                       A, Bv, nidx, w2, g1, be1, m1, v1, g2, be2, m2, v2, out);
}

// Round 12
// 484.973 us; speedup vs baseline: 41.4220x; 1.0192x over previous
//
#include <hip/hip_runtime.h>

#define BB 4
#define CC 64
#define NNN 4096
#define OO 64
#define KK 20
#define EPSF 1e-5f

typedef __attribute__((ext_vector_type(4))) double d4;

// ---------------- K1: xx[n] = sum_c x[c][n]^2 in f64 ----------------
__global__ __launch_bounds__(256) void xx_kernel(const float* __restrict__ x, double* __restrict__ xx) {
    int g = blockIdx.x * 256 + threadIdx.x;          // 0..B*N-1
    int b = g >> 12, n = g & (NNN - 1);
    const float* xp = x + (size_t)b * CC * NNN + n;
    double s = 0.0;
    for (int c = 0; c < CC; ++c) {
        double v = (double)xp[(size_t)c * NNN];
        s += v * v;
    }
    xx[g] = s;
}

// ---------------- K2: per-point projections A = x*w1a^T, Bv = x*(w1b-w1a)^T ----------------
__global__ __launch_bounds__(256) void proj_kernel(const float* __restrict__ x, const float* __restrict__ w1,
                                                   float* __restrict__ A, float* __restrict__ Bv) {
    __shared__ float xs[CC][64];       // [c][p]
    __shared__ float ws1[OO][129];     // padded
    int tid = threadIdx.x;
    int b = blockIdx.x >> 6;
    int p0 = (blockIdx.x & 63) << 6;
    const float* xb = x + (size_t)b * CC * NNN;
    for (int i = tid; i < CC * 16; i += 256) {
        int c = i >> 4, q = i & 15;
        *(float4*)&xs[c][q * 4] = *(const float4*)(xb + (size_t)c * NNN + p0 + q * 4);
    }
    for (int i = tid; i < OO * 32; i += 256) {
        int o = i >> 5, q = i & 31;
        float4 v = *(const float4*)(w1 + o * 128 + q * 4);
        ws1[o][q * 4 + 0] = v.x; ws1[o][q * 4 + 1] = v.y;
        ws1[o][q * 4 + 2] = v.z; ws1[o][q * 4 + 3] = v.w;
    }
    __syncthreads();
    int ti = tid >> 4, tj = tid & 15;
    float aA[4][4] = {{0.f}}, aD[4][4] = {{0.f}};
    for (int c = 0; c < CC; ++c) {
        float4 xv4 = *(const float4*)&xs[c][ti * 4];
        float xv[4] = {xv4.x, xv4.y, xv4.z, xv4.w};
        #pragma unroll
        for (int oo = 0; oo < 4; ++oo) {
            float wa = ws1[tj * 4 + oo][c];
            float wd = ws1[tj * 4 + oo][64 + c] - wa;
            #pragma unroll
            for (int pp = 0; pp < 4; ++pp) {
                aA[pp][oo] = fmaf(xv[pp], wa, aA[pp][oo]);
                aD[pp][oo] = fmaf(xv[pp], wd, aD[pp][oo]);
            }
        }
    }
    size_t base = ((size_t)b * NNN + p0) * 64;
    #pragma unroll
    for (int pp = 0; pp < 4; ++pp) {
        int p = ti * 4 + pp;
        *(float4*)(A  + base + (size_t)p * 64 + tj * 4) = make_float4(aA[pp][0], aA[pp][1], aA[pp][2], aA[pp][3]);
        *(float4*)(Bv + base + (size_t)p * 64 + tj * 4) = make_float4(aD[pp][0], aD[pp][1], aD[pp][2], aD[pp][3]);
    }
}

// ---------------- K3: f64 MFMA distances (probe layout) + sorted-lane top-20 ----------------
// 512 blocks (2/CU, LDS 81408B). Block = 32 rows x 4096 cands, 128-cand tiles.
// Software-pipelined float4 staging: tile t+1's 8 float4 loads issue right after
// barrier B; their L2 latency hides under MFMA(t)+epilogue(t)+select. Loop top
// is vmcnt-wait + 8 ds_write_b128. Selection: wave w rows w*8..w*8+7 (r11-proven).

__device__ __forceinline__ unsigned long long packkey(double d, int j) {
    unsigned long long u = __double_as_longlong(d);
    u ^= (unsigned long long)((long long)u >> 63) | 0x8000000000000000ULL;
    return (u & ~0xFFFULL) | (unsigned long long)(4095 - j);
}

__global__ __launch_bounds__(256) void knn_kernel(const float* __restrict__ x, const double* __restrict__ xx,
                                                  int* __restrict__ idxOut) {
    __shared__ float rowT[CC][48];               // 12288 B (stride 48: 2-way, free)
    __shared__ float candT[CC][136];             // 34816 B (stride 136: 2-way, free)
    __shared__ unsigned long long distK[32][130];// 33280 B
    __shared__ double xxcL[128];                 //  1024 B -> 81408 B total = 2 blocks/CU
    int tid = threadIdx.x;
    int lane = tid & 63, w = tid >> 6;           // 4 waves
    int b  = blockIdx.x >> 7;                    // 128 blocks per batch
    int r0 = (blockIdx.x & 127) * 32;
    const float* xb = x + (size_t)b * CC * NNN;
    const double* xxb = xx + (size_t)b * NNN;

    // ---- layout probe (2 MFMAs, once) ----
    double pv = (double)(lane & 15);
    d4 z4 = {0.0, 0.0, 0.0, 0.0};
    d4 pA = __builtin_amdgcn_mfma_f64_16x16x4f64(pv, 1.0, z4, 0, 0, 0);
    d4 pB = __builtin_amdgcn_mfma_f64_16x16x4f64(1.0, pv, z4, 0, 0, 0);
    int mA0 = (int)(pA[0] * 0.25), mA1 = (int)(pA[1] * 0.25),
        mA2 = (int)(pA[2] * 0.25), mA3 = (int)(pA[3] * 0.25);
    int mB0 = (int)(pB[0] * 0.25), mB1 = (int)(pB[1] * 0.25),
        mB2 = (int)(pB[2] * 0.25), mB3 = (int)(pB[3] * 0.25);

    for (int i = tid; i < CC * 32; i += 256) {   // stage rowT once (f32)
        int c = i >> 5, rr = i & 31;
        rowT[c][rr] = xb[(size_t)c * NNN + r0 + rr];
    }
    int rg = w >> 1, cg = w & 1;
    int lr = lane & 15, lk = lane >> 4;
    int rA0 = rg * 16 + mA0, rA1 = rg * 16 + mA1, rA2 = rg * 16 + mA2, rA3 = rg * 16 + mA3;
    double xr0 = xxb[r0 + rA0], xr1 = xxb[r0 + rA1], xr2 = xxb[r0 + rA2], xr3 = xxb[r0 + rA3];

    // staging registers (static indexing only)
    float4 Lreg0, Lreg1, Lreg2, Lreg3, Lreg4, Lreg5, Lreg6, Lreg7;
    double xxreg = 0.0;
    int srow = tid >> 5;            // base row for p=0 (rows advance by 8 per p)
    int sq   = tid & 31;            // float4 column within the 128-wide tile
    #define ISSUE(T) { \
        const float* gp = xb + (size_t)srow * NNN + (T) * 128 + sq * 4; \
        Lreg0 = *(const float4*)(gp); \
        Lreg1 = *(const float4*)(gp + (size_t)8  * NNN); \
        Lreg2 = *(const float4*)(gp + (size_t)16 * NNN); \
        Lreg3 = *(const float4*)(gp + (size_t)24 * NNN); \
        Lreg4 = *(const float4*)(gp + (size_t)32 * NNN); \
        Lreg5 = *(const float4*)(gp + (size_t)40 * NNN); \
        Lreg6 = *(const float4*)(gp + (size_t)48 * NNN); \
        Lreg7 = *(const float4*)(gp + (size_t)56 * NNN); \
        if (tid < 128) xxreg = xxb[(T) * 128 + tid]; \
    }
    #define WRITE() { \
        *(float4*)&candT[srow     ][sq * 4] = Lreg0; \
        *(float4*)&candT[srow + 8 ][sq * 4] = Lreg1; \
        *(float4*)&candT[srow + 16][sq * 4] = Lreg2; \
        *(float4*)&candT[srow + 24][sq * 4] = Lreg3; \
        *(float4*)&candT[srow + 32][sq * 4] = Lreg4; \
        *(float4*)&candT[srow + 40][sq * 4] = Lreg5; \
        *(float4*)&candT[srow + 48][sq * 4] = Lreg6; \
        *(float4*)&candT[srow + 56][sq * 4] = Lreg7; \
        if (tid < 128) xxcL[tid] = xxreg; \
    }

    // per-wave sorted lists for rows w*8..w*8+7 (ascending across lanes 0..19)
    unsigned long long S0, S1, S2, S3, S4, S5, S6, S7;
    S0 = S1 = S2 = S3 = S4 = S5 = S6 = S7 = (lane < KK) ? 0ULL : ~0ULL;
    unsigned long long T0 = 0, T1 = 0, T2 = 0, T3 = 0, T4 = 0, T5 = 0, T6 = 0, T7 = 0;

    #define SELROW(RL) { \
        for (int hf = 0; hf < 2; ++hf) { \
            unsigned long long key = distK[w * 8 + RL][hf * 64 + lane]; \
            unsigned long long m = __ballot(key > T##RL); \
            while (m) { \
                int src = (int)__builtin_ctzll(m); m &= m - 1; \
                unsigned long long kb = __shfl(key, src); \
                if (kb > T##RL) { \
                    unsigned long long u = __shfl_down(S##RL, 1); \
                    unsigned long long mx = (S##RL < kb) ? kb : S##RL; \
                    S##RL = (u < kb) ? u : mx; \
                    T##RL = __shfl(S##RL, 0); \
                } \
            } \
        } \
    }
    #define SELALL() SELROW(0) SELROW(1) SELROW(2) SELROW(3) SELROW(4) SELROW(5) SELROW(6) SELROW(7)

    ISSUE(0);
    for (int t = 0; t < 32; ++t) {
        int j0 = t * 128;
        __syncthreads();                   // A: candT(t-1) consumed, distK(t-1) ready
        if (t > 0) { SELALL(); }           // select(t-1): reads distK only
        WRITE();                           // vmcnt-wait + 8 ds_write_b128
        __syncthreads();                   // B: candT(t)/xxcL ready
        if (t < 31) { ISSUE(t + 1); }      // loads in flight across MFMA+epilogue+select
        d4 acc0 = {0.0, 0.0, 0.0, 0.0}, acc1 = {0.0, 0.0, 0.0, 0.0};
        d4 acc2 = {0.0, 0.0, 0.0, 0.0}, acc3 = {0.0, 0.0, 0.0, 0.0};
        #pragma unroll
        for (int k = 0; k < 16; ++k) {
            double av = (double)rowT[k * 4 + lk][rg * 16 + lr];
            double b0 = (double)candT[k * 4 + lk][cg * 64 + lr];
            double b1 = (double)candT[k * 4 + lk][cg * 64 + 16 + lr];
            double b2 = (double)candT[k * 4 + lk][cg * 64 + 32 + lr];
            double b3 = (double)candT[k * 4 + lk][cg * 64 + 48 + lr];
            acc0 = __builtin_amdgcn_mfma_f64_16x16x4f64(av, b0, acc0, 0, 0, 0);
            acc1 = __builtin_amdgcn_mfma_f64_16x16x4f64(av, b1, acc1, 0, 0, 0);
            acc2 = __builtin_amdgcn_mfma_f64_16x16x4f64(av, b2, acc2, 0, 0, 0);
            acc3 = __builtin_amdgcn_mfma_f64_16x16x4f64(av, b3, acc3, 0, 0, 0);
        }
        // epilogue: measured labels; chain Q covers cols cg*64 + Q*16 + mB_i
        #define EPI(Q, R) { \
            int col = cg * 64 + Q * 16 + mB##R; \
            distK[rA##R][col] = packkey(2.0 * acc##Q[R] - xr##R - xxcL[col], j0 + col); \
        }
        EPI(0,0) EPI(0,1) EPI(0,2) EPI(0,3)
        EPI(1,0) EPI(1,1) EPI(1,2) EPI(1,3)
        EPI(2,0) EPI(2,1) EPI(2,2) EPI(2,3)
        EPI(3,0) EPI(3,1) EPI(3,2) EPI(3,3)
        #undef EPI
    }
    __syncthreads();                       // final distK ready
    SELALL();
    #undef SELALL
    #undef SELROW
    #undef ISSUE
    #undef WRITE

    if (lane < KK) {                       // lists ascending -> out descending
        size_t base = ((size_t)b * NNN + r0 + w * 8) * KK;
        idxOut[base + 0 * KK + (KK - 1 - lane)] = 4095 - (int)(S0 & 0xFFFULL);
        idxOut[base + 1 * KK + (KK - 1 - lane)] = 4095 - (int)(S1 & 0xFFFULL);
        idxOut[base + 2 * KK + (KK - 1 - lane)] = 4095 - (int)(S2 & 0xFFFULL);
        idxOut[base + 3 * KK + (KK - 1 - lane)] = 4095 - (int)(S3 & 0xFFFULL);
        idxOut[base + 4 * KK + (KK - 1 - lane)] = 4095 - (int)(S4 & 0xFFFULL);
        idxOut[base + 5 * KK + (KK - 1 - lane)] = 4095 - (int)(S5 & 0xFFFULL);
        idxOut[base + 6 * KK + (KK - 1 - lane)] = 4095 - (int)(S6 & 0xFFFULL);
        idxOut[base + 7 * KK + (KK - 1 - lane)] = 4095 - (int)(S7 & 0xFFFULL);
    }
}

// ---------------- K4: h1 = relu(bn1(A[nb]+Bv[n])); h2 = relu(bn2(h1·w2^T)); max over k ----------------
__global__ __launch_bounds__(256) void edge_kernel(const float* __restrict__ A, const float* __restrict__ Bv,
        const int* __restrict__ idx, const float* __restrict__ w2,
        const float* __restrict__ g1, const float* __restrict__ be1, const float* __restrict__ m1, const float* __restrict__ v1,
        const float* __restrict__ g2, const float* __restrict__ be2, const float* __restrict__ m2, const float* __restrict__ v2,
        float* __restrict__ out) {
    __shared__ float h1buf[4][KK][64];
    __shared__ float resT[64][33];
    int tid = threadIdx.x;
    int lane = tid & 63, w = tid >> 6;
    int b = blockIdx.x >> 7;
    int n0 = (blockIdx.x & 127) * 32;
    float s1 = g1[lane] * rsqrtf(v1[lane] + EPSF);
    float bb1 = be1[lane] - m1[lane] * s1;
    float s2 = g2[lane] * rsqrtf(v2[lane] + EPSF);
    float bb2 = be2[lane] - m2[lane] * s2;
    float w2r[64];
    #pragma unroll
    for (int o = 0; o < 64; ++o) w2r[o] = w2[lane * 64 + o];
    for (int p = 0; p < 8; ++p) {
        int n = n0 + w * 8 + p;
        size_t pb = (size_t)b * NNN + n;
        float bv = Bv[pb * 64 + lane];
        const int* ip = idx + pb * KK;
        #pragma unroll
        for (int k = 0; k < KK; ++k) {
            int nb = ip[k];
            float av = A[((size_t)b * NNN + nb) * 64 + lane];
            h1buf[w][k][lane] = fmaxf(0.f, fmaf(av + bv, s1, bb1));
        }
        __syncthreads();
        float mx = -1e30f;
        for (int k = 0; k < KK; ++k) {
            const float4* hb = (const float4*)&h1buf[w][k][0];
            float dot = 0.f;
            #pragma unroll
            for (int o4 = 0; o4 < 16; ++o4) {
                float4 h = hb[o4];
                dot = fmaf(w2r[o4 * 4 + 0], h.x, dot);
                dot = fmaf(w2r[o4 * 4 + 1], h.y, dot);
                dot = fmaf(w2r[o4 * 4 + 2], h.z, dot);
                dot = fmaf(w2r[o4 * 4 + 3], h.w, dot);
            }
            mx = fmaxf(mx, fmaxf(0.f, fmaf(dot, s2, bb2)));
        }
        resT[lane][w * 8 + p] = mx;
        __syncthreads();
    }
    for (int i = tid; i < 64 * 32; i += 256) {
        int o2 = i >> 5, pp = i & 31;
        out[((size_t)b * 64 + o2) * NNN + n0 + pp] = resT[o2][pp];
    }
}

extern "C" void kernel_launch(void* const* d_in, const int* in_sizes, int n_in,
                              void* d_out, int out_size, void* d_ws, size_t ws_size,
                              hipStream_t stream) {
    const float* x   = (const float*)d_in[0];
    const float* w1  = (const float*)d_in[1];
    const float* g1  = (const float*)d_in[2];
    const float* be1 = (const float*)d_in[3];
    const float* m1  = (const float*)d_in[4];
    const float* v1  = (const float*)d_in[5];
    const float* w2  = (const float*)d_in[6];
    const float* g2  = (const float*)d_in[7];
    const float* be2 = (const float*)d_in[8];
    const float* m2  = (const float*)d_in[9];
    const float* v2  = (const float*)d_in[10];
    // ws layout: xx f64 (128KB) | A f32 (4MB) | Bv f32 (4MB) | idx i32 (1.25MB)
    char* ws = (char*)d_ws;
    double* xx = (double*)ws;
    float*  A  = (float*)(ws + 131072);
    float*  Bv = (float*)(ws + 131072 + 4194304);
    int*    nidx = (int*)(ws + 131072 + 2 * 4194304);
    float*  out = (float*)d_out;

    hipLaunchKernelGGL(xx_kernel,   dim3(BB * NNN / 256), dim3(256), 0, stream, x, xx);
    hipLaunchKernelGGL(proj_kernel, dim3(BB * (NNN / 64)), dim3(256), 0, stream, x, w1, A, Bv);
    hipLaunchKernelGGL(knn_kernel,  dim3(BB * (NNN / 32)), dim3(256), 0, stream, x, xx, nidx);
    hipLaunchKernelGGL(edge_kernel, dim3(BB * (NNN / 32)), dim3(256), 0, stream,
                       A, Bv, nidx, w2, g1, be1, m1, v1, g2, be2, m2, v2, out);
}

// Round 13
// 483.027 us; speedup vs baseline: 41.5888x; 1.0040x over previous
//
#include <hip/hip_runtime.h>

#define BB 4
#define CC 64
#define NNN 4096
#define OO 64
#define KK 20
#define EPSF 1e-5f

typedef __attribute__((ext_vector_type(4))) double d4;

// ---------------- K1: xx[n] = sum_c x[c][n]^2 in f64 ----------------
__global__ __launch_bounds__(256) void xx_kernel(const float* __restrict__ x, double* __restrict__ xx) {
    int g = blockIdx.x * 256 + threadIdx.x;          // 0..B*N-1
    int b = g >> 12, n = g & (NNN - 1);
    const float* xp = x + (size_t)b * CC * NNN + n;
    double s = 0.0;
    for (int c = 0; c < CC; ++c) {
        double v = (double)xp[(size_t)c * NNN];
        s += v * v;
    }
    xx[g] = s;
}

// ---------------- K2: per-point projections A = x*w1a^T, Bv = x*(w1b-w1a)^T ----------------
__global__ __launch_bounds__(256) void proj_kernel(const float* __restrict__ x, const float* __restrict__ w1,
                                                   float* __restrict__ A, float* __restrict__ Bv) {
    __shared__ float xs[CC][64];       // [c][p]
    __shared__ float ws1[OO][129];     // padded
    int tid = threadIdx.x;
    int b = blockIdx.x >> 6;
    int p0 = (blockIdx.x & 63) << 6;
    const float* xb = x + (size_t)b * CC * NNN;
    for (int i = tid; i < CC * 16; i += 256) {
        int c = i >> 4, q = i & 15;
        *(float4*)&xs[c][q * 4] = *(const float4*)(xb + (size_t)c * NNN + p0 + q * 4);
    }
    for (int i = tid; i < OO * 32; i += 256) {
        int o = i >> 5, q = i & 31;
        float4 v = *(const float4*)(w1 + o * 128 + q * 4);
        ws1[o][q * 4 + 0] = v.x; ws1[o][q * 4 + 1] = v.y;
        ws1[o][q * 4 + 2] = v.z; ws1[o][q * 4 + 3] = v.w;
    }
    __syncthreads();
    int ti = tid >> 4, tj = tid & 15;
    float aA[4][4] = {{0.f}}, aD[4][4] = {{0.f}};
    for (int c = 0; c < CC; ++c) {
        float4 xv4 = *(const float4*)&xs[c][ti * 4];
        float xv[4] = {xv4.x, xv4.y, xv4.z, xv4.w};
        #pragma unroll
        for (int oo = 0; oo < 4; ++oo) {
            float wa = ws1[tj * 4 + oo][c];
            float wd = ws1[tj * 4 + oo][64 + c] - wa;
            #pragma unroll
            for (int pp = 0; pp < 4; ++pp) {
                aA[pp][oo] = fmaf(xv[pp], wa, aA[pp][oo]);
                aD[pp][oo] = fmaf(xv[pp], wd, aD[pp][oo]);
            }
        }
    }
    size_t base = ((size_t)b * NNN + p0) * 64;
    #pragma unroll
    for (int pp = 0; pp < 4; ++pp) {
        int p = ti * 4 + pp;
        *(float4*)(A  + base + (size_t)p * 64 + tj * 4) = make_float4(aA[pp][0], aA[pp][1], aA[pp][2], aA[pp][3]);
        *(float4*)(Bv + base + (size_t)p * 64 + tj * 4) = make_float4(aD[pp][0], aD[pp][1], aD[pp][2], aD[pp][3]);
    }
}

// ---------------- K3: f64 MFMA distances, 16-row blocks, direct-global B ----------------
// 1024 blocks (4/CU: LDS 37.1KB, VGPR<=128). Block = 16 rows x 4096 cands, 256-cand tiles.
// All 4 waves compute the same 16 rows; wave w covers cols w*64..+63 (4 MFMA chains).
// B-fragments load straight from global (L2-resident; no candT, no staging phase).
// Selection: wave w owns rows w*4..w*4+3 (4x4=16, all covered), r11-proven insert.

__device__ __forceinline__ unsigned long long packkey(double d, int j) {
    unsigned long long u = __double_as_longlong(d);
    u ^= (unsigned long long)((long long)u >> 63) | 0x8000000000000000ULL;
    return (u & ~0xFFFULL) | (unsigned long long)(4095 - j);
}

__global__ __launch_bounds__(256, 4) void knn_kernel(const float* __restrict__ x, const double* __restrict__ xx,
                                                     int* __restrict__ idxOut) {
    __shared__ float rowT[CC][16];               //  4096 B (2-way banks: free)
    __shared__ unsigned long long distK[16][258];// 33024 B -> 37120 B total = 4 blocks/CU
    int tid = threadIdx.x;
    int lane = tid & 63, w = tid >> 6;           // 4 waves
    int b  = blockIdx.x >> 8;                    // 256 blocks per batch
    int r0 = (blockIdx.x & 255) * 16;
    const float* xb = x + (size_t)b * CC * NNN;
    const double* xxb = xx + (size_t)b * NNN;

    // ---- layout probe (2 MFMAs, once) ----
    double pv = (double)(lane & 15);
    d4 z4 = {0.0, 0.0, 0.0, 0.0};
    d4 pA = __builtin_amdgcn_mfma_f64_16x16x4f64(pv, 1.0, z4, 0, 0, 0);
    d4 pB = __builtin_amdgcn_mfma_f64_16x16x4f64(1.0, pv, z4, 0, 0, 0);
    int mA0 = (int)(pA[0] * 0.25), mA1 = (int)(pA[1] * 0.25),
        mA2 = (int)(pA[2] * 0.25), mA3 = (int)(pA[3] * 0.25);
    int mB0 = (int)(pB[0] * 0.25), mB1 = (int)(pB[1] * 0.25),
        mB2 = (int)(pB[2] * 0.25), mB3 = (int)(pB[3] * 0.25);

    for (int i = tid; i < CC * 16; i += 256) {   // stage rowT once (f32)
        int c = i >> 4, rr = i & 15;
        rowT[c][rr] = xb[(size_t)c * NNN + r0 + rr];
    }
    int lr = lane & 15, lk = lane >> 4;
    double xr0 = xxb[r0 + mA0], xr1 = xxb[r0 + mA1],
           xr2 = xxb[r0 + mA2], xr3 = xxb[r0 + mA3];
    __syncthreads();                             // rowT ready

    // per-wave sorted lists for rows w*4..w*4+3 (ascending across lanes 0..19)
    unsigned long long S0, S1, S2, S3;
    S0 = S1 = S2 = S3 = (lane < KK) ? 0ULL : ~0ULL;
    unsigned long long T0 = 0, T1 = 0, T2 = 0, T3 = 0;

    #define SELROW(RL) { \
        for (int hf = 0; hf < 4; ++hf) { \
            unsigned long long key = distK[w * 4 + RL][hf * 64 + lane]; \
            unsigned long long m = __ballot(key > T##RL); \
            while (m) { \
                int src = (int)__builtin_ctzll(m); m &= m - 1; \
                unsigned long long kb = __shfl(key, src); \
                if (kb > T##RL) { \
                    unsigned long long u = __shfl_down(S##RL, 1); \
                    unsigned long long mx = (S##RL < kb) ? kb : S##RL; \
                    S##RL = (u < kb) ? u : mx; \
                    T##RL = __shfl(S##RL, 0); \
                } \
            } \
        } \
    }
    #define SELALL() SELROW(0) SELROW(1) SELROW(2) SELROW(3)

    for (int t = 0; t < 16; ++t) {
        int j0 = t * 256;
        // ---- compute: 4 chains over cols w*64 .. w*64+63; B direct from global (L2) ----
        d4 acc0 = {0.0, 0.0, 0.0, 0.0}, acc1 = {0.0, 0.0, 0.0, 0.0};
        d4 acc2 = {0.0, 0.0, 0.0, 0.0}, acc3 = {0.0, 0.0, 0.0, 0.0};
        const float* gk = xb + (size_t)lk * NNN + j0 + w * 64 + lr;
        #pragma unroll
        for (int k = 0; k < 16; ++k) {
            const float* gp = gk + (size_t)(k * 4) * NNN;
            double av = (double)rowT[k * 4 + lk][lr];
            double b0 = (double)gp[0];
            double b1 = (double)gp[16];
            double b2 = (double)gp[32];
            double b3 = (double)gp[48];
            acc0 = __builtin_amdgcn_mfma_f64_16x16x4f64(av, b0, acc0, 0, 0, 0);
            acc1 = __builtin_amdgcn_mfma_f64_16x16x4f64(av, b1, acc1, 0, 0, 0);
            acc2 = __builtin_amdgcn_mfma_f64_16x16x4f64(av, b2, acc2, 0, 0, 0);
            acc3 = __builtin_amdgcn_mfma_f64_16x16x4f64(av, b3, acc3, 0, 0, 0);
        }
        __syncthreads();                   // A: select(t-1) finished reading distK
        // ---- epilogue: measured labels; chain Q covers col w*64 + Q*16 + mB_i ----
        #define EPI(Q, R) { \
            int col = w * 64 + Q * 16 + mB##R; \
            double xq = xxb[j0 + col]; \
            distK[mA##R][col] = packkey(2.0 * acc##Q[R] - xr##R - xq, j0 + col); \
        }
        EPI(0,0) EPI(0,1) EPI(0,2) EPI(0,3)
        EPI(1,0) EPI(1,1) EPI(1,2) EPI(1,3)
        EPI(2,0) EPI(2,1) EPI(2,2) EPI(2,3)
        EPI(3,0) EPI(3,1) EPI(3,2) EPI(3,3)
        #undef EPI
        __syncthreads();                   // B: distK(t) ready
        SELALL();                          // select(t); next compute overlaps naturally
    }
    #undef SELALL
    #undef SELROW

    if (lane < KK) {                       // lists ascending -> out descending
        size_t base = ((size_t)b * NNN + r0 + w * 4) * KK;
        idxOut[base + 0 * KK + (KK - 1 - lane)] = 4095 - (int)(S0 & 0xFFFULL);
        idxOut[base + 1 * KK + (KK - 1 - lane)] = 4095 - (int)(S1 & 0xFFFULL);
        idxOut[base + 2 * KK + (KK - 1 - lane)] = 4095 - (int)(S2 & 0xFFFULL);
        idxOut[base + 3 * KK + (KK - 1 - lane)] = 4095 - (int)(S3 & 0xFFFULL);
    }
}

// ---------------- K4: h1 = relu(bn1(A[nb]+Bv[n])); h2 = relu(bn2(h1·w2^T)); max over k ----------------
__global__ __launch_bounds__(256) void edge_kernel(const float* __restrict__ A, const float* __restrict__ Bv,
        const int* __restrict__ idx, const float* __restrict__ w2,
        const float* __restrict__ g1, const float* __restrict__ be1, const float* __restrict__ m1, const float* __restrict__ v1,
        const float* __restrict__ g2, const float* __restrict__ be2, const float* __restrict__ m2, const float* __restrict__ v2,
        float* __restrict__ out) {
    __shared__ float h1buf[4][KK][64];
    __shared__ float resT[64][33];
    int tid = threadIdx.x;
    int lane = tid & 63, w = tid >> 6;
    int b = blockIdx.x >> 7;
    int n0 = (blockIdx.x & 127) * 32;
    float s1 = g1[lane] * rsqrtf(v1[lane] + EPSF);
    float bb1 = be1[lane] - m1[lane] * s1;
    float s2 = g2[lane] * rsqrtf(v2[lane] + EPSF);
    float bb2 = be2[lane] - m2[lane] * s2;
    float w2r[64];
    #pragma unroll
    for (int o = 0; o < 64; ++o) w2r[o] = w2[lane * 64 + o];
    for (int p = 0; p < 8; ++p) {
        int n = n0 + w * 8 + p;
        size_t pb = (size_t)b * NNN + n;
        float bv = Bv[pb * 64 + lane];
        const int* ip = idx + pb * KK;
        #pragma unroll
        for (int k = 0; k < KK; ++k) {
            int nb = ip[k];
            float av = A[((size_t)b * NNN + nb) * 64 + lane];
            h1buf[w][k][lane] = fmaxf(0.f, fmaf(av + bv, s1, bb1));
        }
        __syncthreads();
        float mx = -1e30f;
        for (int k = 0; k < KK; ++k) {
            const float4* hb = (const float4*)&h1buf[w][k][0];
            float dot = 0.f;
            #pragma unroll
            for (int o4 = 0; o4 < 16; ++o4) {
                float4 h = hb[o4];
                dot = fmaf(w2r[o4 * 4 + 0], h.x, dot);
                dot = fmaf(w2r[o4 * 4 + 1], h.y, dot);
                dot = fmaf(w2r[o4 * 4 + 2], h.z, dot);
                dot = fmaf(w2r[o4 * 4 + 3], h.w, dot);
            }
            mx = fmaxf(mx, fmaxf(0.f, fmaf(dot, s2, bb2)));
        }
        resT[lane][w * 8 + p] = mx;
        __syncthreads();
    }
    for (int i = tid; i < 64 * 32; i += 256) {
        int o2 = i >> 5, pp = i & 31;
        out[((size_t)b * 64 + o2) * NNN + n0 + pp] = resT[o2][pp];
    }
}

extern "C" void kernel_launch(void* const* d_in, const int* in_sizes, int n_in,
                              void* d_out, int out_size, void* d_ws, size_t ws_size,
                              hipStream_t stream) {
    const float* x   = (const float*)d_in[0];
    const float* w1  = (const float*)d_in[1];
    const float* g1  = (const float*)d_in[2];
    const float* be1 = (const float*)d_in[3];
    const float* m1  = (const float*)d_in[4];
    const float* v1  = (const float*)d_in[5];
    const float* w2  = (const float*)d_in[6];
    const float* g2  = (const float*)d_in[7];
    const float* be2 = (const float*)d_in[8];
    const float* m2  = (const float*)d_in[9];
    const float* v2  = (const float*)d_in[10];
    // ws layout: xx f64 (128KB) | A f32 (4MB) | Bv f32 (4MB) | idx i32 (1.25MB)
    char* ws = (char*)d_ws;
    double* xx = (double*)ws;
    float*  A  = (float*)(ws + 131072);
    float*  Bv = (float*)(ws + 131072 + 4194304);
    int*    nidx = (int*)(ws + 131072 + 2 * 4194304);
    float*  out = (float*)d_out;

    hipLaunchKernelGGL(xx_kernel,   dim3(BB * NNN / 256), dim3(256), 0, stream, x, xx);
    hipLaunchKernelGGL(proj_kernel, dim3(BB * (NNN / 64)), dim3(256), 0, stream, x, w1, A, Bv);
    hipLaunchKernelGGL(knn_kernel,  dim3(BB * (NNN / 16)), dim3(256), 0, stream, x, xx, nidx);
    hipLaunchKernelGGL(edge_kernel, dim3(BB * (NNN / 32)), dim3(256), 0, stream,
                       A, Bv, nidx, w2, g1, be1, m1, v1, g2, be2, m2, v2, out);
}